// Round 1
// baseline (911.342 us; speedup 1.0000x reference)
//
#include <hip/hip_runtime.h>

#define B_ 256
#define E_ 1024
#define H_ 1024
#define F_ 2048
#define L_ 196
#define A_ 512
#define ML (B_ * L_)   // 50176

typedef __attribute__((ext_vector_type(8))) short short8;
typedef __attribute__((ext_vector_type(4))) float f32x4;

__device__ __forceinline__ unsigned short f2bf(float x) {
  unsigned u = __float_as_uint(x);
  unsigned r = (u + 0x7FFFu + ((u >> 16) & 1u)) >> 16;   // RNE
  return (unsigned short)r;
}
__device__ __forceinline__ float fast_tanh(float x) {
  x = fminf(fmaxf(x, -15.f), 15.f);
  float e = __expf(2.f * x);
  return (e - 1.f) / (e + 1.f);
}
__device__ __forceinline__ float sigmoidf_(float x) {
  return 1.f / (1.f + __expf(-x));
}

// ---------------- cast Wa f32 -> bf16 (one-time tiny pass) ----------------
__global__ void cast_wa_k(const float* __restrict__ Wa, unsigned short* __restrict__ WaB) {
  int i = (blockIdx.x * 256 + threadIdx.x) * 4;   // covers A_*F_ = 1,048,576
  float4 v = *reinterpret_cast<const float4*>(Wa + i);
  ushort4 o;
  o.x = f2bf(v.x); o.y = f2bf(v.y); o.z = f2bf(v.z); o.w = f2bf(v.w);
  *reinterpret_cast<ushort4*>(WaB + i) = o;
}

// ---------------- h_linear = h @ Wha^T + bha : [B,A] ----------------
__global__ __launch_bounds__(256) void hlin_k(const float* __restrict__ h,
                                              const float* __restrict__ Wha,
                                              const float* __restrict__ bha,
                                              float* __restrict__ hlin) {
  int b = blockIdx.x;
  int lane = threadIdx.x & 63, wid = threadIdx.x >> 6;
  const float* hb = h + (size_t)b * H_ + lane * 16;
  float4 hv0 = *reinterpret_cast<const float4*>(hb + 0);
  float4 hv1 = *reinterpret_cast<const float4*>(hb + 4);
  float4 hv2 = *reinterpret_cast<const float4*>(hb + 8);
  float4 hv3 = *reinterpret_cast<const float4*>(hb + 12);
  for (int a = wid; a < A_; a += 4) {
    const float* wr = Wha + (size_t)a * H_ + lane * 16;
    float4 w0 = *reinterpret_cast<const float4*>(wr + 0);
    float4 w1 = *reinterpret_cast<const float4*>(wr + 4);
    float4 w2 = *reinterpret_cast<const float4*>(wr + 8);
    float4 w3 = *reinterpret_cast<const float4*>(wr + 12);
    float s = w0.x * hv0.x + w0.y * hv0.y + w0.z * hv0.z + w0.w * hv0.w
            + w1.x * hv1.x + w1.y * hv1.y + w1.z * hv1.z + w1.w * hv1.w
            + w2.x * hv2.x + w2.y * hv2.y + w2.z * hv2.z + w2.w * hv2.w
            + w3.x * hv3.x + w3.y * hv3.y + w3.z * hv3.z + w3.w * hv3.w;
    #pragma unroll
    for (int off = 32; off; off >>= 1) s += __shfl_xor(s, off);
    if (lane == 0) hlin[(size_t)b * A_ + a] = s + bha[a];
  }
}

// ---------------- score GEMM: scores[m] = sum_a Wo[a]*tanh(att@Wa^T + ba + hlin) ----------------
// M=50176, N=512, K=2048. 128x128 tile, BK=64, 4 waves (2x2), mfma 16x16x32 bf16.
__global__ __launch_bounds__(256, 2)
void score_gemm_k(const float* __restrict__ att, const unsigned short* __restrict__ WaB,
                  const float* __restrict__ hlin, const float* __restrict__ ba,
                  const float* __restrict__ Wo, float* __restrict__ scores) {
  __shared__ unsigned short As[128 * 64];
  __shared__ unsigned short Bs[128 * 64];
  const int tid = threadIdx.x;
  const int lane = tid & 63, wid = tid >> 6;
  const int wm = wid >> 1, wn = wid & 1;
  const int m0 = blockIdx.y * 128;
  const int n0 = blockIdx.x * 128;
  const int g16 = lane >> 4, l16 = lane & 15;

  f32x4 acc[4][4] = {};

  for (int k0 = 0; k0 < F_; k0 += 64) {
    // B tile (bf16 Wa) -> LDS via async direct load; layout = linear = row-major [128][64]
    #pragma unroll
    for (int it = 0; it < 4; ++it) {
      int idx = it * 256 + tid;          // 0..1023 ; byte off = idx*16
      int row = idx >> 3, kc = idx & 7;
      __builtin_amdgcn_global_load_lds(
          (const __attribute__((address_space(1))) void*)(WaB + (size_t)(n0 + row) * F_ + k0 + kc * 8),
          (__attribute__((address_space(3))) void*)(&Bs[idx * 8]),
          16, 0, 0);
    }
    // A tile: f32 load + convert to bf16
    #pragma unroll
    for (int it = 0; it < 8; ++it) {
      int idx = it * 256 + tid;          // 0..2047
      int row = idx >> 4, kf = idx & 15;
      float4 v = *reinterpret_cast<const float4*>(att + (size_t)(m0 + row) * F_ + k0 + kf * 4);
      ushort4 o;
      o.x = f2bf(v.x); o.y = f2bf(v.y); o.z = f2bf(v.z); o.w = f2bf(v.w);
      *reinterpret_cast<ushort4*>(&As[row * 64 + kf * 4]) = o;
    }
    __syncthreads();

    #pragma unroll
    for (int ks = 0; ks < 2; ++ks) {
      const int kb = ks * 32 + g16 * 8;
      short8 af[4], bfr[4];
      #pragma unroll
      for (int mi = 0; mi < 4; ++mi)
        af[mi] = *reinterpret_cast<const short8*>(&As[(wm * 64 + mi * 16 + l16) * 64 + kb]);
      #pragma unroll
      for (int ni = 0; ni < 4; ++ni)
        bfr[ni] = *reinterpret_cast<const short8*>(&Bs[(wn * 64 + ni * 16 + l16) * 64 + kb]);
      #pragma unroll
      for (int mi = 0; mi < 4; ++mi)
        #pragma unroll
        for (int ni = 0; ni < 4; ++ni)
          acc[mi][ni] = __builtin_amdgcn_mfma_f32_16x16x32_bf16(af[mi], bfr[ni], acc[mi][ni], 0, 0, 0);
    }
    __syncthreads();
  }

  // epilogue: tanh + Wo-weighted reduce over this block's 128 a-columns
  float wo_v[4], ba_v[4];
  int a_v[4];
  #pragma unroll
  for (int ni = 0; ni < 4; ++ni) {
    int a = n0 + wn * 64 + ni * 16 + l16;
    a_v[ni] = a; wo_v[ni] = Wo[a]; ba_v[ni] = ba[a];
  }
  #pragma unroll
  for (int mi = 0; mi < 4; ++mi) {
    float rs[4];
    #pragma unroll
    for (int j = 0; j < 4; ++j) {
      int m = m0 + wm * 64 + mi * 16 + g16 * 4 + j;
      int b = m / L_;
      const float* hb = hlin + (size_t)b * A_;
      float s = 0.f;
      #pragma unroll
      for (int ni = 0; ni < 4; ++ni) {
        float v = acc[mi][ni][j] + ba_v[ni] + hb[a_v[ni]];
        s += fast_tanh(v) * wo_v[ni];
      }
      rs[j] = s;
    }
    #pragma unroll
    for (int off = 1; off < 16; off <<= 1) {
      #pragma unroll
      for (int j = 0; j < 4; ++j) rs[j] += __shfl_xor(rs[j], off);
    }
    if (l16 == 0) {
      #pragma unroll
      for (int j = 0; j < 4; ++j) {
        int m = m0 + wm * 64 + mi * 16 + g16 * 4 + j;
        atomicAdd(&scores[m], rs[j]);
      }
    }
  }
}

// ---------------- softmax over L per batch row ----------------
__global__ void softmax_k(const float* __restrict__ scores, float* __restrict__ w) {
  int b = blockIdx.x, lane = threadIdx.x;
  float v[4];
  float m = -1e30f;
  int n = 0;
  for (int l = lane; l < L_; l += 64) { v[n] = scores[b * L_ + l]; m = fmaxf(m, v[n]); ++n; }
  #pragma unroll
  for (int off = 32; off; off >>= 1) m = fmaxf(m, __shfl_xor(m, off));
  float s = 0.f;
  for (int i = 0; i < n; ++i) { v[i] = __expf(v[i] - m); s += v[i]; }
  #pragma unroll
  for (int off = 32; off; off >>= 1) s += __shfl_xor(s, off);
  float inv = 1.f / s;
  int i = 0;
  for (int l = lane; l < L_; l += 64) w[b * L_ + l] = v[i++] * inv;
}

// ---------------- z = sum_l w[b,l] * att_seq[b,l,:] ----------------
__global__ __launch_bounds__(256) void z_k(const float* __restrict__ att,
                                           const float* __restrict__ w,
                                           float* __restrict__ z) {
  int b = blockIdx.y;
  int f0 = blockIdx.x * 1024 + threadIdx.x * 4;
  const float* base = att + (size_t)b * L_ * F_ + f0;
  const float* wb = w + b * L_;
  float ax = 0.f, ay = 0.f, az = 0.f, aw = 0.f;
  #pragma unroll 4
  for (int l = 0; l < L_; ++l) {
    float wl = wb[l];
    float4 a = *reinterpret_cast<const float4*>(base + (size_t)l * F_);
    ax += wl * a.x; ay += wl * a.y; az += wl * a.z; aw += wl * a.w;
  }
  float4 o; o.x = ax; o.y = ay; o.z = az; o.w = aw;
  *reinterpret_cast<float4*>(z + (size_t)b * F_ + f0) = o;
}

// ---------------- gates GEMM: sums = xt@Wi^T + h@Wh^T + z@Wz^T + biases ----------------
// M=256, N=4096, K=4096 (segments 1024/1024/2048). Same tile structure.
__global__ __launch_bounds__(256, 2)
void gates_gemm_k(const float* __restrict__ xt, const float* __restrict__ h, const float* __restrict__ z,
                  const float* __restrict__ Wi, const float* __restrict__ Wh, const float* __restrict__ Wz,
                  const float* __restrict__ bi, const float* __restrict__ bh, const float* __restrict__ bz,
                  float* __restrict__ sums) {
  __shared__ unsigned short As[128 * 64];
  __shared__ unsigned short Bs[128 * 64];
  const int tid = threadIdx.x;
  const int lane = tid & 63, wid = tid >> 6;
  const int wm = wid >> 1, wn = wid & 1;
  const int m0 = blockIdx.y * 128;
  const int n0 = blockIdx.x * 128;
  const int g16 = lane >> 4, l16 = lane & 15;

  f32x4 acc[4][4] = {};

  for (int k0 = 0; k0 < 4096; k0 += 64) {
    const float* aseg;
    const float* wseg;
    int lda, kk;
    if (k0 < 1024)      { aseg = xt; wseg = Wi; lda = 1024; kk = k0; }
    else if (k0 < 2048) { aseg = h;  wseg = Wh; lda = 1024; kk = k0 - 1024; }
    else                { aseg = z;  wseg = Wz; lda = 2048; kk = k0 - 2048; }
    #pragma unroll
    for (int it = 0; it < 8; ++it) {
      int idx = it * 256 + tid;
      int row = idx >> 4, kf = idx & 15;
      float4 v = *reinterpret_cast<const float4*>(aseg + (size_t)(m0 + row) * lda + kk + kf * 4);
      ushort4 o;
      o.x = f2bf(v.x); o.y = f2bf(v.y); o.z = f2bf(v.z); o.w = f2bf(v.w);
      *reinterpret_cast<ushort4*>(&As[row * 64 + kf * 4]) = o;
      float4 u = *reinterpret_cast<const float4*>(wseg + (size_t)(n0 + row) * lda + kk + kf * 4);
      ushort4 p;
      p.x = f2bf(u.x); p.y = f2bf(u.y); p.z = f2bf(u.z); p.w = f2bf(u.w);
      *reinterpret_cast<ushort4*>(&Bs[row * 64 + kf * 4]) = p;
    }
    __syncthreads();

    #pragma unroll
    for (int ks = 0; ks < 2; ++ks) {
      const int kb = ks * 32 + g16 * 8;
      short8 af[4], bfr[4];
      #pragma unroll
      for (int mi = 0; mi < 4; ++mi)
        af[mi] = *reinterpret_cast<const short8*>(&As[(wm * 64 + mi * 16 + l16) * 64 + kb]);
      #pragma unroll
      for (int ni = 0; ni < 4; ++ni)
        bfr[ni] = *reinterpret_cast<const short8*>(&Bs[(wn * 64 + ni * 16 + l16) * 64 + kb]);
      #pragma unroll
      for (int mi = 0; mi < 4; ++mi)
        #pragma unroll
        for (int ni = 0; ni < 4; ++ni)
          acc[mi][ni] = __builtin_amdgcn_mfma_f32_16x16x32_bf16(af[mi], bfr[ni], acc[mi][ni], 0, 0, 0);
    }
    __syncthreads();
  }

  #pragma unroll
  for (int ni = 0; ni < 4; ++ni) {
    int col = n0 + wn * 64 + ni * 16 + l16;
    float bsum = bi[col] + bh[col] + bz[col];
    #pragma unroll
    for (int mi = 0; mi < 4; ++mi)
      #pragma unroll
      for (int j = 0; j < 4; ++j) {
        int m = m0 + wm * 64 + mi * 16 + g16 * 4 + j;
        sums[(size_t)m * 4096 + col] = acc[mi][ni][j] + bsum;
      }
  }
}

// ---------------- gates + zoneout elementwise ----------------
__global__ void final_k(const float* __restrict__ sums, const float* __restrict__ h,
                        const float* __restrict__ c, float* __restrict__ out) {
  int i = blockIdx.x * 256 + threadIdx.x;   // 0 .. B_*H_-1
  int b = i >> 10, hh = i & 1023;
  const float* srow = sums + (size_t)b * 4096;
  float ig = sigmoidf_(srow[hh]);
  float fg = sigmoidf_(srow[1024 + hh]);
  float og = sigmoidf_(srow[2048 + hh]);
  float g  = fast_tanh(srow[3072 + hh]);
  float cv = c[i], hv = h[i];
  float nc = 0.5f * cv + 0.5f * (fg * cv + ig * g);
  float nh = 0.5f * hv + 0.5f * (og * fast_tanh(nc));
  out[i] = nh;
  out[B_ * H_ + i] = nh;
  out[2 * B_ * H_ + i] = nc;
}

extern "C" void kernel_launch(void* const* d_in, const int* in_sizes, int n_in,
                              void* d_out, int out_size, void* d_ws, size_t ws_size,
                              hipStream_t stream) {
  const float* xt  = (const float*)d_in[0];
  const float* att = (const float*)d_in[1];
  const float* h   = (const float*)d_in[2];
  const float* c   = (const float*)d_in[3];
  const float* Wi  = (const float*)d_in[4];
  const float* bi  = (const float*)d_in[5];
  const float* Wh  = (const float*)d_in[6];
  const float* bh  = (const float*)d_in[7];
  const float* Wz  = (const float*)d_in[8];
  const float* bz  = (const float*)d_in[9];
  const float* Wa  = (const float*)d_in[10];
  const float* ba  = (const float*)d_in[11];
  const float* Wha = (const float*)d_in[12];
  const float* bha = (const float*)d_in[13];
  const float* Wo  = (const float*)d_in[14];
  // bo (d_in[15]) is a constant shift under softmax -> dropped.

  char* ws = (char*)d_ws;
  unsigned short* WaB = (unsigned short*)(ws);            // 2 MB
  float* scores = (float*)(ws + ((size_t)2 << 20));       // 0.2 MB
  float* w      = (float*)(ws + ((size_t)3 << 20));       // 0.2 MB
  float* hlin   = (float*)(ws + ((size_t)4 << 20));       // 0.5 MB
  float* z      = (float*)(ws + ((size_t)5 << 20));       // 2 MB
  float* sums   = (float*)(ws + ((size_t)8 << 20));       // 4 MB
  float* out    = (float*)d_out;

  hipMemsetAsync(scores, 0, ML * sizeof(float), stream);
  cast_wa_k<<<1024, 256, 0, stream>>>(Wa, WaB);
  hlin_k<<<B_, 256, 0, stream>>>(h, Wha, bha, hlin);
  score_gemm_k<<<dim3(A_ / 128, ML / 128), 256, 0, stream>>>(att, WaB, hlin, ba, Wo, scores);
  softmax_k<<<B_, 64, 0, stream>>>(scores, w);
  z_k<<<dim3(F_ / 1024, B_), 256, 0, stream>>>(att, w, z);
  gates_gemm_k<<<dim3(4096 / 128, B_ / 128), 256, 0, stream>>>(xt, h, z, Wi, Wh, Wz, bi, bh, bz, sums);
  final_k<<<B_ * H_ / 256, 256, 0, stream>>>(sums, h, c, out);
}

// Round 3
// 571.216 us; speedup vs baseline: 1.5954x; 1.5954x over previous
//
#include <hip/hip_runtime.h>

#define B_ 256
#define E_ 1024
#define H_ 1024
#define F_ 2048
#define L_ 196
#define A_ 512
#define ML (B_ * L_)   // 50176

typedef __attribute__((ext_vector_type(8))) short short8;
typedef __attribute__((ext_vector_type(4))) float f32x4;

__device__ __forceinline__ unsigned short f2bf(float x) {
  unsigned u = __float_as_uint(x);
  unsigned r = (u + 0x7FFFu + ((u >> 16) & 1u)) >> 16;   // RNE
  return (unsigned short)r;
}
__device__ __forceinline__ float bf2f(unsigned short u) {
  return __uint_as_float((unsigned)u << 16);
}
__device__ __forceinline__ float fast_tanh(float x) {
  x = fminf(fmaxf(x, -15.f), 15.f);
  float e = __expf(2.f * x);
  return (e - 1.f) / (e + 1.f);
}
__device__ __forceinline__ float sigmoidf_(float x) {
  return 1.f / (1.f + __expf(-x));
}

#define GLOAD_LDS(gptr, lptr) \
  __builtin_amdgcn_global_load_lds( \
      (const __attribute__((address_space(1))) void*)(gptr), \
      (__attribute__((address_space(3))) void*)(lptr), 16, 0, 0)

// ---------------- streaming casts f32 -> bf16 ----------------
// grid MUST be B_*L_*F_ / 2048 = 50176 blocks.
__global__ void cast_att_k(const float* __restrict__ src, unsigned short* __restrict__ dst) {
  size_t i = ((size_t)blockIdx.x * 256 + threadIdx.x) * 8;   // covers B_*L_*F_
  float4 a = *reinterpret_cast<const float4*>(src + i);
  float4 b = *reinterpret_cast<const float4*>(src + i + 4);
  short8 o;
  o[0] = (short)f2bf(a.x); o[1] = (short)f2bf(a.y); o[2] = (short)f2bf(a.z); o[3] = (short)f2bf(a.w);
  o[4] = (short)f2bf(b.x); o[5] = (short)f2bf(b.y); o[6] = (short)f2bf(b.z); o[7] = (short)f2bf(b.w);
  *reinterpret_cast<short8*>(dst + i) = o;
}

__global__ void cast_wa_k(const float* __restrict__ Wa, unsigned short* __restrict__ WaB) {
  int i = (blockIdx.x * 256 + threadIdx.x) * 4;   // covers A_*F_ = 1,048,576
  float4 v = *reinterpret_cast<const float4*>(Wa + i);
  ushort4 o;
  o.x = f2bf(v.x); o.y = f2bf(v.y); o.z = f2bf(v.z); o.w = f2bf(v.w);
  *reinterpret_cast<ushort4*>(WaB + i) = o;
}

// WgB[4096][4096] = [Wi(1024) | Wh(1024) | Wz(2048)] per row
__global__ void cast_wg_k(const float* __restrict__ Wi, const float* __restrict__ Wh,
                          const float* __restrict__ Wz, unsigned short* __restrict__ WgB) {
  size_t i = ((size_t)blockIdx.x * 256 + threadIdx.x) * 8;   // covers 4096*4096
  int row = (int)(i >> 12);
  int col = (int)(i & 4095);
  const float* src;
  if (col < 1024)       src = Wi + (size_t)row * 1024 + col;
  else if (col < 2048)  src = Wh + (size_t)row * 1024 + (col - 1024);
  else                  src = Wz + (size_t)row * 2048 + (col - 2048);
  float4 a = *reinterpret_cast<const float4*>(src);
  float4 b = *reinterpret_cast<const float4*>(src + 4);
  short8 o;
  o[0] = (short)f2bf(a.x); o[1] = (short)f2bf(a.y); o[2] = (short)f2bf(a.z); o[3] = (short)f2bf(a.w);
  o[4] = (short)f2bf(b.x); o[5] = (short)f2bf(b.y); o[6] = (short)f2bf(b.z); o[7] = (short)f2bf(b.w);
  *reinterpret_cast<short8*>(WgB + i) = o;
}

// AgB[256][4096] cols 0..1023 = xt, 1024..2047 = h (z written later by z_k)
__global__ void cast_xh_k(const float* __restrict__ xt, const float* __restrict__ h,
                          unsigned short* __restrict__ AgB) {
  int i = (blockIdx.x * 256 + threadIdx.x) * 8;   // covers 256*2048
  int row = i >> 11;
  int col = i & 2047;
  const float* src = (col < 1024) ? (xt + row * 1024 + col) : (h + row * 1024 + (col - 1024));
  float4 a = *reinterpret_cast<const float4*>(src);
  float4 b = *reinterpret_cast<const float4*>(src + 4);
  short8 o;
  o[0] = (short)f2bf(a.x); o[1] = (short)f2bf(a.y); o[2] = (short)f2bf(a.z); o[3] = (short)f2bf(a.w);
  o[4] = (short)f2bf(b.x); o[5] = (short)f2bf(b.y); o[6] = (short)f2bf(b.z); o[7] = (short)f2bf(b.w);
  *reinterpret_cast<short8*>(AgB + (size_t)row * 4096 + col) = o;
}

// ---------------- h_linear = h @ Wha^T + bha : [B,A] ----------------
__global__ __launch_bounds__(256) void hlin_k(const float* __restrict__ h,
                                              const float* __restrict__ Wha,
                                              const float* __restrict__ bha,
                                              float* __restrict__ hlin) {
  int b = blockIdx.x;
  int lane = threadIdx.x & 63, wid = threadIdx.x >> 6;
  const float* hb = h + (size_t)b * H_ + lane * 16;
  float4 hv0 = *reinterpret_cast<const float4*>(hb + 0);
  float4 hv1 = *reinterpret_cast<const float4*>(hb + 4);
  float4 hv2 = *reinterpret_cast<const float4*>(hb + 8);
  float4 hv3 = *reinterpret_cast<const float4*>(hb + 12);
  for (int a = wid; a < A_; a += 4) {
    const float* wr = Wha + (size_t)a * H_ + lane * 16;
    float4 w0 = *reinterpret_cast<const float4*>(wr + 0);
    float4 w1 = *reinterpret_cast<const float4*>(wr + 4);
    float4 w2 = *reinterpret_cast<const float4*>(wr + 8);
    float4 w3 = *reinterpret_cast<const float4*>(wr + 12);
    float s = w0.x * hv0.x + w0.y * hv0.y + w0.z * hv0.z + w0.w * hv0.w
            + w1.x * hv1.x + w1.y * hv1.y + w1.z * hv1.z + w1.w * hv1.w
            + w2.x * hv2.x + w2.y * hv2.y + w2.z * hv2.z + w2.w * hv2.w
            + w3.x * hv3.x + w3.y * hv3.y + w3.z * hv3.z + w3.w * hv3.w;
    #pragma unroll
    for (int off = 32; off; off >>= 1) s += __shfl_xor(s, off);
    if (lane == 0) hlin[(size_t)b * A_ + a] = s + bha[a];
  }
}

// ---------------- score GEMM: scores[m] = sum_a Wo[a]*tanh(att@Wa^T + ba + hlin) ----------------
// M=50176, N=512, K=2048. 128x128 tile, BK=64, 4 waves, mfma 16x16x32 bf16. m97 structure.
template <bool PRE>
__global__ __launch_bounds__(256)
void score_gemm_k(const float* __restrict__ att, const unsigned short* __restrict__ attB,
                  const unsigned short* __restrict__ WaB,
                  const float* __restrict__ hlin, const float* __restrict__ ba,
                  const float* __restrict__ Wo, float* __restrict__ scores) {
  __shared__ unsigned short As[128 * 64];
  __shared__ unsigned short Bs[128 * 64];
  const int tid = threadIdx.x;
  const int lane = tid & 63, wid = tid >> 6;
  const int wm = wid >> 1, wn = wid & 1;
  // XCD-aware swizzle: 1568 blocks, 1568 % 8 == 0 -> each XCD gets 196 consecutive
  // logical ids (49 M-tiles x 4 N-tiles, N fastest -> A-tile reused within XCD L2).
  const int logical = (blockIdx.x & 7) * 196 + (blockIdx.x >> 3);
  const int m0 = (logical >> 2) * 128;
  const int n0 = (logical & 3) * 128;
  const int g16 = lane >> 4, l16 = lane & 15;

  f32x4 acc[4][4] = {};

  for (int k0 = 0; k0 < F_; k0 += 64) {
    #pragma unroll
    for (int it = 0; it < 4; ++it) {
      int idx = it * 256 + tid;          // 0..1023; row=idx>>3, chunk kc=idx&7
      int row = idx >> 3, kc = idx & 7;
      GLOAD_LDS(WaB + (size_t)(n0 + row) * F_ + k0 + kc * 8, &Bs[idx * 8]);
      if (PRE)
        GLOAD_LDS(attB + (size_t)(m0 + row) * F_ + k0 + kc * 8, &As[idx * 8]);
    }
    if (!PRE) {
      #pragma unroll
      for (int it = 0; it < 8; ++it) {
        int idx = it * 256 + tid;
        int row = idx >> 4, kf = idx & 15;
        float4 v = *reinterpret_cast<const float4*>(att + (size_t)(m0 + row) * F_ + k0 + kf * 4);
        ushort4 o;
        o.x = f2bf(v.x); o.y = f2bf(v.y); o.z = f2bf(v.z); o.w = f2bf(v.w);
        *reinterpret_cast<ushort4*>(&As[row * 64 + kf * 4]) = o;
      }
    }
    __syncthreads();

    #pragma unroll
    for (int ks = 0; ks < 2; ++ks) {
      const int kb = ks * 32 + g16 * 8;
      short8 af[4], bfr[4];
      #pragma unroll
      for (int mi = 0; mi < 4; ++mi)
        af[mi] = *reinterpret_cast<const short8*>(&As[(wm * 64 + mi * 16 + l16) * 64 + kb]);
      #pragma unroll
      for (int ni = 0; ni < 4; ++ni)
        bfr[ni] = *reinterpret_cast<const short8*>(&Bs[(wn * 64 + ni * 16 + l16) * 64 + kb]);
      #pragma unroll
      for (int mi = 0; mi < 4; ++mi)
        #pragma unroll
        for (int ni = 0; ni < 4; ++ni)
          acc[mi][ni] = __builtin_amdgcn_mfma_f32_16x16x32_bf16(af[mi], bfr[ni], acc[mi][ni], 0, 0, 0);
    }
    __syncthreads();
  }

  // epilogue: tanh + Wo-weighted reduce over this block's 128 a-columns
  float wo_v[4], ba_v[4];
  int a_v[4];
  #pragma unroll
  for (int ni = 0; ni < 4; ++ni) {
    int a = n0 + wn * 64 + ni * 16 + l16;
    a_v[ni] = a; wo_v[ni] = Wo[a]; ba_v[ni] = ba[a];
  }
  #pragma unroll
  for (int mi = 0; mi < 4; ++mi) {
    float rs[4];
    #pragma unroll
    for (int j = 0; j < 4; ++j) {
      int m = m0 + wm * 64 + mi * 16 + g16 * 4 + j;
      int b = m / L_;
      const float* hb = hlin + (size_t)b * A_;
      float s = 0.f;
      #pragma unroll
      for (int ni = 0; ni < 4; ++ni) {
        float v = acc[mi][ni][j] + ba_v[ni] + hb[a_v[ni]];
        s += fast_tanh(v) * wo_v[ni];
      }
      rs[j] = s;
    }
    #pragma unroll
    for (int off = 1; off < 16; off <<= 1) {
      #pragma unroll
      for (int j = 0; j < 4; ++j) rs[j] += __shfl_xor(rs[j], off);
    }
    if (l16 == 0) {
      #pragma unroll
      for (int j = 0; j < 4; ++j) {
        int m = m0 + wm * 64 + mi * 16 + g16 * 4 + j;
        atomicAdd(&scores[m], rs[j]);
      }
    }
  }
}

// ---------------- softmax over L per batch row ----------------
__global__ void softmax_k(const float* __restrict__ scores, float* __restrict__ w) {
  int b = blockIdx.x, lane = threadIdx.x;
  float v[4];
  float m = -1e30f;
  int n = 0;
  for (int l = lane; l < L_; l += 64) { v[n] = scores[b * L_ + l]; m = fmaxf(m, v[n]); ++n; }
  #pragma unroll
  for (int off = 32; off; off >>= 1) m = fmaxf(m, __shfl_xor(m, off));
  float s = 0.f;
  for (int i = 0; i < n; ++i) { v[i] = __expf(v[i] - m); s += v[i]; }
  #pragma unroll
  for (int off = 32; off; off >>= 1) s += __shfl_xor(s, off);
  float inv = 1.f / s;
  int i = 0;
  for (int l = lane; l < L_; l += 64) w[b * L_ + l] = v[i++] * inv;
}

// ---------------- z = sum_l w[b,l] * att_seq[b,l,:]  -> bf16 into AgB cols 2048.. ----------------
template <bool PRE>
__global__ __launch_bounds__(256) void z_k(const float* __restrict__ att,
                                           const unsigned short* __restrict__ attB,
                                           const float* __restrict__ w,
                                           unsigned short* __restrict__ AgB) {
  int b = blockIdx.y;
  int f0 = blockIdx.x * 1024 + threadIdx.x * 4;
  const float* wb = w + b * L_;
  float ax = 0.f, ay = 0.f, az = 0.f, aw = 0.f;
  if (PRE) {
    const unsigned short* base = attB + (size_t)b * L_ * F_ + f0;
    #pragma unroll 4
    for (int l = 0; l < L_; ++l) {
      float wl = wb[l];
      ushort4 a = *reinterpret_cast<const ushort4*>(base + (size_t)l * F_);
      ax += wl * bf2f(a.x); ay += wl * bf2f(a.y); az += wl * bf2f(a.z); aw += wl * bf2f(a.w);
    }
  } else {
    const float* base = att + (size_t)b * L_ * F_ + f0;
    #pragma unroll 4
    for (int l = 0; l < L_; ++l) {
      float wl = wb[l];
      float4 a = *reinterpret_cast<const float4*>(base + (size_t)l * F_);
      ax += wl * a.x; ay += wl * a.y; az += wl * a.z; aw += wl * a.w;
    }
  }
  ushort4 o;
  o.x = f2bf(ax); o.y = f2bf(ay); o.z = f2bf(az); o.w = f2bf(aw);
  *reinterpret_cast<ushort4*>(AgB + (size_t)b * 4096 + 2048 + f0) = o;
}

// ---------------- gates GEMM (bf16): sums = AgB @ WgB^T + biases ----------------
// M=256, N=4096, K=4096. BM=64, BN=128, BK=64, 4 waves (2x2), each wave 32x64.
__global__ __launch_bounds__(256)
void gates_gemm_k(const unsigned short* __restrict__ AgB, const unsigned short* __restrict__ WgB,
                  const float* __restrict__ bi, const float* __restrict__ bh,
                  const float* __restrict__ bz, float* __restrict__ sums) {
  __shared__ unsigned short As[64 * 64];
  __shared__ unsigned short Bs[128 * 64];
  const int tid = threadIdx.x;
  const int lane = tid & 63, wid = tid >> 6;
  const int wm = wid >> 1, wn = wid & 1;
  const int m0 = blockIdx.y * 64;
  const int n0 = blockIdx.x * 128;
  const int g16 = lane >> 4, l16 = lane & 15;

  f32x4 acc[2][4] = {};

  for (int k0 = 0; k0 < 4096; k0 += 64) {
    #pragma unroll
    for (int it = 0; it < 2; ++it) {
      int idx = it * 256 + tid;          // 0..511
      int row = idx >> 3, kc = idx & 7;
      GLOAD_LDS(AgB + (size_t)(m0 + row) * 4096 + k0 + kc * 8, &As[idx * 8]);
    }
    #pragma unroll
    for (int it = 0; it < 4; ++it) {
      int idx = it * 256 + tid;          // 0..1023
      int row = idx >> 3, kc = idx & 7;
      GLOAD_LDS(WgB + (size_t)(n0 + row) * 4096 + k0 + kc * 8, &Bs[idx * 8]);
    }
    __syncthreads();

    #pragma unroll
    for (int ks = 0; ks < 2; ++ks) {
      const int kb = ks * 32 + g16 * 8;
      short8 af[2], bfr[4];
      #pragma unroll
      for (int mi = 0; mi < 2; ++mi)
        af[mi] = *reinterpret_cast<const short8*>(&As[(wm * 32 + mi * 16 + l16) * 64 + kb]);
      #pragma unroll
      for (int ni = 0; ni < 4; ++ni)
        bfr[ni] = *reinterpret_cast<const short8*>(&Bs[(wn * 64 + ni * 16 + l16) * 64 + kb]);
      #pragma unroll
      for (int mi = 0; mi < 2; ++mi)
        #pragma unroll
        for (int ni = 0; ni < 4; ++ni)
          acc[mi][ni] = __builtin_amdgcn_mfma_f32_16x16x32_bf16(af[mi], bfr[ni], acc[mi][ni], 0, 0, 0);
    }
    __syncthreads();
  }

  #pragma unroll
  for (int ni = 0; ni < 4; ++ni) {
    int col = n0 + wn * 64 + ni * 16 + l16;
    float bsum = bi[col] + bh[col] + bz[col];
    #pragma unroll
    for (int mi = 0; mi < 2; ++mi)
      #pragma unroll
      for (int j = 0; j < 4; ++j) {
        int m = m0 + wm * 32 + mi * 16 + g16 * 4 + j;
        sums[(size_t)m * 4096 + col] = acc[mi][ni][j] + bsum;
      }
  }
}

// ---------------- gates + zoneout elementwise ----------------
__global__ void final_k(const float* __restrict__ sums, const float* __restrict__ h,
                        const float* __restrict__ c, float* __restrict__ out) {
  int i = blockIdx.x * 256 + threadIdx.x;   // 0 .. B_*H_-1
  int b = i >> 10, hh = i & 1023;
  const float* srow = sums + (size_t)b * 4096;
  float ig = sigmoidf_(srow[hh]);
  float fg = sigmoidf_(srow[1024 + hh]);
  float og = sigmoidf_(srow[2048 + hh]);
  float g  = fast_tanh(srow[3072 + hh]);
  float cv = c[i], hv = h[i];
  float nc = 0.5f * cv + 0.5f * (fg * cv + ig * g);
  float nh = 0.5f * hv + 0.5f * (og * fast_tanh(nc));
  out[i] = nh;
  out[B_ * H_ + i] = nh;
  out[2 * B_ * H_ + i] = nc;
}

extern "C" void kernel_launch(void* const* d_in, const int* in_sizes, int n_in,
                              void* d_out, int out_size, void* d_ws, size_t ws_size,
                              hipStream_t stream) {
  const float* xt  = (const float*)d_in[0];
  const float* att = (const float*)d_in[1];
  const float* h   = (const float*)d_in[2];
  const float* c   = (const float*)d_in[3];
  const float* Wi  = (const float*)d_in[4];
  const float* bi  = (const float*)d_in[5];
  const float* Wh  = (const float*)d_in[6];
  const float* bh  = (const float*)d_in[7];
  const float* Wz  = (const float*)d_in[8];
  const float* bz  = (const float*)d_in[9];
  const float* Wa  = (const float*)d_in[10];
  const float* ba  = (const float*)d_in[11];
  const float* Wha = (const float*)d_in[12];
  const float* bha = (const float*)d_in[13];
  const float* Wo  = (const float*)d_in[14];
  // bo (d_in[15]) is a constant shift under softmax -> dropped.

  char* ws = (char*)d_ws;
  const size_t MB = (size_t)1 << 20;
  unsigned short* WaB = (unsigned short*)(ws);                 // 2 MB
  unsigned short* WgB = (unsigned short*)(ws + 2 * MB);        // 32 MB
  unsigned short* AgB = (unsigned short*)(ws + 34 * MB);       // 2 MB
  float* hlin   = (float*)(ws + 36 * MB);                      // 0.5 MB
  float* scores = (float*)(ws + 37 * MB);                      // 0.2 MB
  float* w      = (float*)(ws + 38 * MB);                      // 0.2 MB
  float* sums   = (float*)(ws + 39 * MB);                      // 4 MB
  unsigned short* attB = (unsigned short*)(ws + 43 * MB);      // 196 MB (optional)
  const bool PRE = ws_size >= 240 * MB;
  float* out = (float*)d_out;

  hipMemsetAsync(scores, 0, ML * sizeof(float), stream);
  cast_wa_k<<<1024, 256, 0, stream>>>(Wa, WaB);
  cast_wg_k<<<8192, 256, 0, stream>>>(Wi, Wh, Wz, WgB);
  cast_xh_k<<<256, 256, 0, stream>>>(xt, h, AgB);
  hlin_k<<<B_, 256, 0, stream>>>(h, Wha, bha, hlin);
  if (PRE) {
    // B_*L_*F_ / (256*8) = 50176 blocks (exact).
    cast_att_k<<<ML, 256, 0, stream>>>(att, attB);
    score_gemm_k<true><<<(ML / 128) * (A_ / 128), 256, 0, stream>>>(att, attB, WaB, hlin, ba, Wo, scores);
  } else {
    score_gemm_k<false><<<(ML / 128) * (A_ / 128), 256, 0, stream>>>(att, attB, WaB, hlin, ba, Wo, scores);
  }
  softmax_k<<<B_, 64, 0, stream>>>(scores, w);
  if (PRE) z_k<true><<<dim3(2, B_), 256, 0, stream>>>(att, attB, w, AgB);
  else     z_k<false><<<dim3(2, B_), 256, 0, stream>>>(att, attB, w, AgB);
  gates_gemm_k<<<dim3(32, 4), 256, 0, stream>>>(AgB, WgB, bi, bh, bz, sums);
  final_k<<<B_ * H_ / 256, 256, 0, stream>>>(sums, h, c, out);
}

// Round 4
// 539.534 us; speedup vs baseline: 1.6891x; 1.0587x over previous
//
#include <hip/hip_runtime.h>

#define B_ 256
#define E_ 1024
#define H_ 1024
#define F_ 2048
#define L_ 196
#define A_ 512
#define ML (B_ * L_)   // 50176

typedef __attribute__((ext_vector_type(8))) short short8;
typedef __attribute__((ext_vector_type(4))) float f32x4;

__device__ __forceinline__ unsigned short f2bf(float x) {
  unsigned u = __float_as_uint(x);
  unsigned r = (u + 0x7FFFu + ((u >> 16) & 1u)) >> 16;   // RNE
  return (unsigned short)r;
}
__device__ __forceinline__ float bf2f(unsigned short u) {
  return __uint_as_float((unsigned)u << 16);
}
__device__ __forceinline__ float fast_tanh(float x) {
  x = fminf(fmaxf(x, -15.f), 15.f);
  float e = __expf(2.f * x);
  return (e - 1.f) / (e + 1.f);
}
__device__ __forceinline__ float sigmoidf_(float x) {
  return 1.f / (1.f + __expf(-x));
}

#define GLOAD_LDS(gptr, lptr) \
  __builtin_amdgcn_global_load_lds( \
      (const __attribute__((address_space(1))) void*)(gptr), \
      (__attribute__((address_space(3))) void*)(lptr), 16, 0, 0)

// ---------------- streaming casts f32 -> bf16 ----------------
// grid MUST be B_*L_*F_ / 2048 = 50176 blocks.
__global__ void cast_att_k(const float* __restrict__ src, unsigned short* __restrict__ dst) {
  size_t i = ((size_t)blockIdx.x * 256 + threadIdx.x) * 8;   // covers B_*L_*F_
  float4 a = *reinterpret_cast<const float4*>(src + i);
  float4 b = *reinterpret_cast<const float4*>(src + i + 4);
  short8 o;
  o[0] = (short)f2bf(a.x); o[1] = (short)f2bf(a.y); o[2] = (short)f2bf(a.z); o[3] = (short)f2bf(a.w);
  o[4] = (short)f2bf(b.x); o[5] = (short)f2bf(b.y); o[6] = (short)f2bf(b.z); o[7] = (short)f2bf(b.w);
  *reinterpret_cast<short8*>(dst + i) = o;
}

__global__ void cast_wa_k(const float* __restrict__ Wa, unsigned short* __restrict__ WaB) {
  int i = (blockIdx.x * 256 + threadIdx.x) * 4;   // covers A_*F_ = 1,048,576
  float4 v = *reinterpret_cast<const float4*>(Wa + i);
  ushort4 o;
  o.x = f2bf(v.x); o.y = f2bf(v.y); o.z = f2bf(v.z); o.w = f2bf(v.w);
  *reinterpret_cast<ushort4*>(WaB + i) = o;
}

// WgB[4096][4096] = [Wi(1024) | Wh(1024) | Wz(2048)] per row
__global__ void cast_wg_k(const float* __restrict__ Wi, const float* __restrict__ Wh,
                          const float* __restrict__ Wz, unsigned short* __restrict__ WgB) {
  size_t i = ((size_t)blockIdx.x * 256 + threadIdx.x) * 8;   // covers 4096*4096
  int row = (int)(i >> 12);
  int col = (int)(i & 4095);
  const float* src;
  if (col < 1024)       src = Wi + (size_t)row * 1024 + col;
  else if (col < 2048)  src = Wh + (size_t)row * 1024 + (col - 1024);
  else                  src = Wz + (size_t)row * 2048 + (col - 2048);
  float4 a = *reinterpret_cast<const float4*>(src);
  float4 b = *reinterpret_cast<const float4*>(src + 4);
  short8 o;
  o[0] = (short)f2bf(a.x); o[1] = (short)f2bf(a.y); o[2] = (short)f2bf(a.z); o[3] = (short)f2bf(a.w);
  o[4] = (short)f2bf(b.x); o[5] = (short)f2bf(b.y); o[6] = (short)f2bf(b.z); o[7] = (short)f2bf(b.w);
  *reinterpret_cast<short8*>(WgB + i) = o;
}

// AgB[256][4096] cols 0..1023 = xt, 1024..2047 = h (z written later by z kernels)
__global__ void cast_xh_k(const float* __restrict__ xt, const float* __restrict__ h,
                          unsigned short* __restrict__ AgB) {
  int i = (blockIdx.x * 256 + threadIdx.x) * 8;   // covers 256*2048
  int row = i >> 11;
  int col = i & 2047;
  const float* src = (col < 1024) ? (xt + row * 1024 + col) : (h + row * 1024 + (col - 1024));
  float4 a = *reinterpret_cast<const float4*>(src);
  float4 b = *reinterpret_cast<const float4*>(src + 4);
  short8 o;
  o[0] = (short)f2bf(a.x); o[1] = (short)f2bf(a.y); o[2] = (short)f2bf(a.z); o[3] = (short)f2bf(a.w);
  o[4] = (short)f2bf(b.x); o[5] = (short)f2bf(b.y); o[6] = (short)f2bf(b.z); o[7] = (short)f2bf(b.w);
  *reinterpret_cast<short8*>(AgB + (size_t)row * 4096 + col) = o;
}

// ---------------- h_linear = h @ Wha^T + bha : [B,A] ----------------
__global__ __launch_bounds__(256) void hlin_k(const float* __restrict__ h,
                                              const float* __restrict__ Wha,
                                              const float* __restrict__ bha,
                                              float* __restrict__ hlin) {
  int b = blockIdx.x;
  int lane = threadIdx.x & 63, wid = threadIdx.x >> 6;
  const float* hb = h + (size_t)b * H_ + lane * 16;
  float4 hv0 = *reinterpret_cast<const float4*>(hb + 0);
  float4 hv1 = *reinterpret_cast<const float4*>(hb + 4);
  float4 hv2 = *reinterpret_cast<const float4*>(hb + 8);
  float4 hv3 = *reinterpret_cast<const float4*>(hb + 12);
  for (int a = wid; a < A_; a += 4) {
    const float* wr = Wha + (size_t)a * H_ + lane * 16;
    float4 w0 = *reinterpret_cast<const float4*>(wr + 0);
    float4 w1 = *reinterpret_cast<const float4*>(wr + 4);
    float4 w2 = *reinterpret_cast<const float4*>(wr + 8);
    float4 w3 = *reinterpret_cast<const float4*>(wr + 12);
    float s = w0.x * hv0.x + w0.y * hv0.y + w0.z * hv0.z + w0.w * hv0.w
            + w1.x * hv1.x + w1.y * hv1.y + w1.z * hv1.z + w1.w * hv1.w
            + w2.x * hv2.x + w2.y * hv2.y + w2.z * hv2.z + w2.w * hv2.w
            + w3.x * hv3.x + w3.y * hv3.y + w3.z * hv3.z + w3.w * hv3.w;
    #pragma unroll
    for (int off = 32; off; off >>= 1) s += __shfl_xor(s, off);
    if (lane == 0) hlin[(size_t)b * A_ + a] = s + bha[a];
  }
}

// ---------------- score GEMM: scores[m] = sum_a Wo[a]*tanh(att@Wa^T + ba + hlin) ----------------
// M=50176, N=512, K=2048. 128x128 tile, BK=64, 4 waves.
// T3-min 2-phase: double-buffered LDS, STAGE(t+1) issued before compute(t).
// LDS slot swizzle (16B slots): LDS slot s of row r holds global slot s^(r&7);
// read of global group g uses slot g^(r&7). Involution -> both-sides consistent (rule #21).
template <bool PRE>
__global__ __launch_bounds__(256, 2)
void score_gemm_k(const float* __restrict__ att, const unsigned short* __restrict__ attB,
                  const unsigned short* __restrict__ WaB,
                  const float* __restrict__ hlin, const float* __restrict__ ba,
                  const float* __restrict__ Wo, float* __restrict__ scores) {
  __shared__ unsigned short As[2][128 * 64];
  __shared__ unsigned short Bs[2][128 * 64];
  const int tid = threadIdx.x;
  const int lane = tid & 63, wid = tid >> 6;
  const int wm = wid >> 1, wn = wid & 1;
  // XCD-aware swizzle: 1568 blocks % 8 == 0; N fastest -> A-tile reuse within XCD L2.
  const int logical = (blockIdx.x & 7) * 196 + (blockIdx.x >> 3);
  const int m0 = (logical >> 2) * 128;
  const int n0 = (logical & 3) * 128;
  const int g16 = lane >> 4, l16 = lane & 15;
  const int l7 = l16 & 7;

  f32x4 acc[4][4] = {};

  // staging: idx 0..1023, row=idx>>3, lds slot = idx&7, global slot kc = slot^(row&7)
#define STAGE_SC(BUF, KK)                                                               \
  {                                                                                     \
    _Pragma("unroll")                                                                   \
    for (int it = 0; it < 4; ++it) {                                                    \
      int idx = it * 256 + tid;                                                         \
      int row = idx >> 3;                                                               \
      int kc = (idx & 7) ^ (row & 7);                                                   \
      GLOAD_LDS(WaB + (size_t)(n0 + row) * F_ + (KK) + kc * 8, &Bs[BUF][idx * 8]);      \
      if (PRE)                                                                          \
        GLOAD_LDS(attB + (size_t)(m0 + row) * F_ + (KK) + kc * 8, &As[BUF][idx * 8]);   \
    }                                                                                   \
    if (!PRE) {                                                                         \
      _Pragma("unroll")                                                                 \
      for (int it = 0; it < 8; ++it) {                                                  \
        int idx = it * 256 + tid;                                                       \
        int row = idx >> 4, kf = idx & 15;                                              \
        float4 v = *reinterpret_cast<const float4*>(att + (size_t)(m0 + row) * F_ + (KK) + kf * 4); \
        ushort4 o;                                                                      \
        o.x = f2bf(v.x); o.y = f2bf(v.y); o.z = f2bf(v.z); o.w = f2bf(v.w);             \
        int el = row * 64 + (((kf >> 1) ^ (row & 7)) << 3) + ((kf & 1) << 2);           \
        *reinterpret_cast<ushort4*>(&As[BUF][el]) = o;                                  \
      }                                                                                 \
    }                                                                                   \
  }

  int cur = 0;
  STAGE_SC(0, 0);
  __syncthreads();   // emits s_waitcnt vmcnt(0) lgkmcnt(0) + s_barrier

  for (int k0 = 0; k0 < F_; k0 += 64) {
    if (k0 + 64 < F_) STAGE_SC(cur ^ 1, k0 + 64);
    #pragma unroll
    for (int ks = 0; ks < 2; ++ks) {
      const int kg = ks * 4 + g16;                 // 16B-slot group of this fragment
      const int ko = (kg ^ l7) << 3;               // swizzled element offset
      short8 af[4], bfr[4];
      #pragma unroll
      for (int mi = 0; mi < 4; ++mi)
        af[mi] = *reinterpret_cast<const short8*>(&As[cur][(wm * 64 + mi * 16 + l16) * 64 + ko]);
      #pragma unroll
      for (int ni = 0; ni < 4; ++ni)
        bfr[ni] = *reinterpret_cast<const short8*>(&Bs[cur][(wn * 64 + ni * 16 + l16) * 64 + ko]);
      #pragma unroll
      for (int mi = 0; mi < 4; ++mi)
        #pragma unroll
        for (int ni = 0; ni < 4; ++ni)
          acc[mi][ni] = __builtin_amdgcn_mfma_f32_16x16x32_bf16(af[mi], bfr[ni], acc[mi][ni], 0, 0, 0);
    }
    __syncthreads();   // drains this iter's staged loads (vmcnt 0) + all ds reads
    cur ^= 1;
  }
#undef STAGE_SC

  // epilogue: tanh + Wo-weighted reduce over this block's 128 a-columns
  float wo_v[4], ba_v[4];
  int a_v[4];
  #pragma unroll
  for (int ni = 0; ni < 4; ++ni) {
    int a = n0 + wn * 64 + ni * 16 + l16;
    a_v[ni] = a; wo_v[ni] = Wo[a]; ba_v[ni] = ba[a];
  }
  #pragma unroll
  for (int mi = 0; mi < 4; ++mi) {
    float rs[4];
    #pragma unroll
    for (int j = 0; j < 4; ++j) {
      int m = m0 + wm * 64 + mi * 16 + g16 * 4 + j;
      int b = m / L_;
      const float* hb = hlin + (size_t)b * A_;
      float s = 0.f;
      #pragma unroll
      for (int ni = 0; ni < 4; ++ni) {
        float v = acc[mi][ni][j] + ba_v[ni] + hb[a_v[ni]];
        s += fast_tanh(v) * wo_v[ni];
      }
      rs[j] = s;
    }
    #pragma unroll
    for (int off = 1; off < 16; off <<= 1) {
      #pragma unroll
      for (int j = 0; j < 4; ++j) rs[j] += __shfl_xor(rs[j], off);
    }
    if (l16 == 0) {
      #pragma unroll
      for (int j = 0; j < 4; ++j) {
        int m = m0 + wm * 64 + mi * 16 + g16 * 4 + j;
        atomicAdd(&scores[m], rs[j]);
      }
    }
  }
}

// ---------------- softmax over L per batch row ----------------
__global__ void softmax_k(const float* __restrict__ scores, float* __restrict__ w) {
  int b = blockIdx.x, lane = threadIdx.x;
  float v[4];
  float m = -1e30f;
  int n = 0;
  for (int l = lane; l < L_; l += 64) { v[n] = scores[b * L_ + l]; m = fmaxf(m, v[n]); ++n; }
  #pragma unroll
  for (int off = 32; off; off >>= 1) m = fmaxf(m, __shfl_xor(m, off));
  float s = 0.f;
  for (int i = 0; i < n; ++i) { v[i] = __expf(v[i] - m); s += v[i]; }
  #pragma unroll
  for (int off = 32; off; off >>= 1) s += __shfl_xor(s, off);
  float inv = 1.f / s;
  int i = 0;
  for (int l = lane; l < L_; l += 64) w[b * L_ + l] = v[i++] * inv;
}

// ---------------- z = sum_l w[b,l] * att_seq[b,l,:]  -> bf16 into AgB cols 2048.. ----------------
__global__ __launch_bounds__(256) void z_bf_k(const unsigned short* __restrict__ attB,
                                              const float* __restrict__ w,
                                              unsigned short* __restrict__ AgB) {
  int b = blockIdx.x;
  int f0 = threadIdx.x * 8;
  const unsigned short* base = attB + (size_t)b * L_ * F_ + f0;
  const float* wb = w + b * L_;
  float acc[8] = {};
  #pragma unroll 4
  for (int l = 0; l < L_; ++l) {
    float wl = wb[l];
    short8 a = *reinterpret_cast<const short8*>(base + (size_t)l * F_);
    #pragma unroll
    for (int j = 0; j < 8; ++j) acc[j] += wl * bf2f((unsigned short)a[j]);
  }
  short8 o;
  #pragma unroll
  for (int j = 0; j < 8; ++j) o[j] = (short)f2bf(acc[j]);
  *reinterpret_cast<short8*>(AgB + (size_t)b * 4096 + 2048 + f0) = o;
}

__global__ __launch_bounds__(256) void z_f32_k(const float* __restrict__ att,
                                               const float* __restrict__ w,
                                               unsigned short* __restrict__ AgB) {
  int b = blockIdx.y;
  int f0 = blockIdx.x * 1024 + threadIdx.x * 4;
  const float* base = att + (size_t)b * L_ * F_ + f0;
  const float* wb = w + b * L_;
  float ax = 0.f, ay = 0.f, az = 0.f, aw = 0.f;
  #pragma unroll 4
  for (int l = 0; l < L_; ++l) {
    float wl = wb[l];
    float4 a = *reinterpret_cast<const float4*>(base + (size_t)l * F_);
    ax += wl * a.x; ay += wl * a.y; az += wl * a.z; aw += wl * a.w;
  }
  ushort4 o;
  o.x = f2bf(ax); o.y = f2bf(ay); o.z = f2bf(az); o.w = f2bf(aw);
  *reinterpret_cast<ushort4*>(AgB + (size_t)b * 4096 + 2048 + f0) = o;
}

// ---------------- gates GEMM (bf16): sums = AgB @ WgB^T + biases ----------------
// M=256, N=4096, K=4096. BM=64, BN=128, BK=64. Same 2-phase dbuf + slot swizzle.
__global__ __launch_bounds__(256, 3)
void gates_gemm_k(const unsigned short* __restrict__ AgB, const unsigned short* __restrict__ WgB,
                  const float* __restrict__ bi, const float* __restrict__ bh,
                  const float* __restrict__ bz, float* __restrict__ sums) {
  __shared__ unsigned short As[2][64 * 64];
  __shared__ unsigned short Bs[2][128 * 64];
  const int tid = threadIdx.x;
  const int lane = tid & 63, wid = tid >> 6;
  const int wm = wid >> 1, wn = wid & 1;
  const int m0 = blockIdx.y * 64;
  const int n0 = blockIdx.x * 128;
  const int g16 = lane >> 4, l16 = lane & 15;
  const int l7 = l16 & 7;

  f32x4 acc[2][4] = {};

#define STAGE_GG(BUF, KK)                                                               \
  {                                                                                     \
    _Pragma("unroll")                                                                   \
    for (int it = 0; it < 2; ++it) {                                                    \
      int idx = it * 256 + tid;                                                         \
      int row = idx >> 3;                                                               \
      int kc = (idx & 7) ^ (row & 7);                                                   \
      GLOAD_LDS(AgB + (size_t)(m0 + row) * 4096 + (KK) + kc * 8, &As[BUF][idx * 8]);    \
    }                                                                                   \
    _Pragma("unroll")                                                                   \
    for (int it = 0; it < 4; ++it) {                                                    \
      int idx = it * 256 + tid;                                                         \
      int row = idx >> 3;                                                               \
      int kc = (idx & 7) ^ (row & 7);                                                   \
      GLOAD_LDS(WgB + (size_t)(n0 + row) * 4096 + (KK) + kc * 8, &Bs[BUF][idx * 8]);    \
    }                                                                                   \
  }

  int cur = 0;
  STAGE_GG(0, 0);
  __syncthreads();

  for (int k0 = 0; k0 < 4096; k0 += 64) {
    if (k0 + 64 < 4096) STAGE_GG(cur ^ 1, k0 + 64);
    #pragma unroll
    for (int ks = 0; ks < 2; ++ks) {
      const int kg = ks * 4 + g16;
      const int ko = (kg ^ l7) << 3;
      short8 af[2], bfr[4];
      #pragma unroll
      for (int mi = 0; mi < 2; ++mi)
        af[mi] = *reinterpret_cast<const short8*>(&As[cur][(wm * 32 + mi * 16 + l16) * 64 + ko]);
      #pragma unroll
      for (int ni = 0; ni < 4; ++ni)
        bfr[ni] = *reinterpret_cast<const short8*>(&Bs[cur][(wn * 64 + ni * 16 + l16) * 64 + ko]);
      #pragma unroll
      for (int mi = 0; mi < 2; ++mi)
        #pragma unroll
        for (int ni = 0; ni < 4; ++ni)
          acc[mi][ni] = __builtin_amdgcn_mfma_f32_16x16x32_bf16(af[mi], bfr[ni], acc[mi][ni], 0, 0, 0);
    }
    __syncthreads();
    cur ^= 1;
  }
#undef STAGE_GG

  #pragma unroll
  for (int ni = 0; ni < 4; ++ni) {
    int col = n0 + wn * 64 + ni * 16 + l16;
    float bsum = bi[col] + bh[col] + bz[col];
    #pragma unroll
    for (int mi = 0; mi < 2; ++mi)
      #pragma unroll
      for (int j = 0; j < 4; ++j) {
        int m = m0 + wm * 32 + mi * 16 + g16 * 4 + j;
        sums[(size_t)m * 4096 + col] = acc[mi][ni][j] + bsum;
      }
  }
}

// ---------------- gates + zoneout elementwise ----------------
__global__ void final_k(const float* __restrict__ sums, const float* __restrict__ h,
                        const float* __restrict__ c, float* __restrict__ out) {
  int i = blockIdx.x * 256 + threadIdx.x;   // 0 .. B_*H_-1
  int b = i >> 10, hh = i & 1023;
  const float* srow = sums + (size_t)b * 4096;
  float ig = sigmoidf_(srow[hh]);
  float fg = sigmoidf_(srow[1024 + hh]);
  float og = sigmoidf_(srow[2048 + hh]);
  float g  = fast_tanh(srow[3072 + hh]);
  float cv = c[i], hv = h[i];
  float nc = 0.5f * cv + 0.5f * (fg * cv + ig * g);
  float nh = 0.5f * hv + 0.5f * (og * fast_tanh(nc));
  out[i] = nh;
  out[B_ * H_ + i] = nh;
  out[2 * B_ * H_ + i] = nc;
}

extern "C" void kernel_launch(void* const* d_in, const int* in_sizes, int n_in,
                              void* d_out, int out_size, void* d_ws, size_t ws_size,
                              hipStream_t stream) {
  const float* xt  = (const float*)d_in[0];
  const float* att = (const float*)d_in[1];
  const float* h   = (const float*)d_in[2];
  const float* c   = (const float*)d_in[3];
  const float* Wi  = (const float*)d_in[4];
  const float* bi  = (const float*)d_in[5];
  const float* Wh  = (const float*)d_in[6];
  const float* bh  = (const float*)d_in[7];
  const float* Wz  = (const float*)d_in[8];
  const float* bz  = (const float*)d_in[9];
  const float* Wa  = (const float*)d_in[10];
  const float* ba  = (const float*)d_in[11];
  const float* Wha = (const float*)d_in[12];
  const float* bha = (const float*)d_in[13];
  const float* Wo  = (const float*)d_in[14];
  // bo (d_in[15]) is a constant shift under softmax -> dropped.

  char* ws = (char*)d_ws;
  const size_t MB = (size_t)1 << 20;
  unsigned short* WaB = (unsigned short*)(ws);                 // 2 MB
  unsigned short* WgB = (unsigned short*)(ws + 2 * MB);        // 32 MB
  unsigned short* AgB = (unsigned short*)(ws + 34 * MB);       // 2 MB
  float* hlin   = (float*)(ws + 36 * MB);                      // 0.5 MB
  float* scores = (float*)(ws + 37 * MB);                      // 0.2 MB
  float* w      = (float*)(ws + 38 * MB);                      // 0.2 MB
  float* sums   = (float*)(ws + 39 * MB);                      // 4 MB
  unsigned short* attB = (unsigned short*)(ws + 43 * MB);      // 196 MB (optional)
  const bool PRE = ws_size >= 240 * MB;
  float* out = (float*)d_out;

  hipMemsetAsync(scores, 0, ML * sizeof(float), stream);
  cast_wa_k<<<1024, 256, 0, stream>>>(Wa, WaB);
  cast_wg_k<<<8192, 256, 0, stream>>>(Wi, Wh, Wz, WgB);
  cast_xh_k<<<256, 256, 0, stream>>>(xt, h, AgB);
  hlin_k<<<B_, 256, 0, stream>>>(h, Wha, bha, hlin);
  if (PRE) {
    // B_*L_*F_ / (256*8) = 50176 blocks (exact).
    cast_att_k<<<ML, 256, 0, stream>>>(att, attB);
    score_gemm_k<true><<<(ML / 128) * (A_ / 128), 256, 0, stream>>>(att, attB, WaB, hlin, ba, Wo, scores);
  } else {
    score_gemm_k<false><<<(ML / 128) * (A_ / 128), 256, 0, stream>>>(att, attB, WaB, hlin, ba, Wo, scores);
  }
  softmax_k<<<B_, 64, 0, stream>>>(scores, w);
  if (PRE) z_bf_k<<<B_, 256, 0, stream>>>(attB, w, AgB);
  else     z_f32_k<<<dim3(2, B_), 256, 0, stream>>>(att, w, AgB);
  gates_gemm_k<<<dim3(32, 4), 256, 0, stream>>>(AgB, WgB, bi, bh, bz, sums);
  final_k<<<B_ * H_ / 256, 256, 0, stream>>>(sums, h, c, out);
}

// Round 6
// 421.416 us; speedup vs baseline: 2.1626x; 1.2803x over previous
//
#include <hip/hip_runtime.h>

#define B_ 256
#define E_ 1024
#define H_ 1024
#define F_ 2048
#define L_ 196
#define A_ 512
#define ML (B_ * L_)   // 50176

typedef __attribute__((ext_vector_type(8))) short short8;
typedef __attribute__((ext_vector_type(4))) float f32x4;

__device__ __forceinline__ unsigned short f2bf(float x) {
  unsigned u = __float_as_uint(x);
  unsigned r = (u + 0x7FFFu + ((u >> 16) & 1u)) >> 16;   // RNE
  return (unsigned short)r;
}
__device__ __forceinline__ float bf2f(unsigned short u) {
  return __uint_as_float((unsigned)u << 16);
}
__device__ __forceinline__ float fast_tanh(float x) {
  x = fminf(fmaxf(x, -15.f), 15.f);
  float e = __expf(2.f * x);
  return (e - 1.f) / (e + 1.f);
}
__device__ __forceinline__ float sigmoidf_(float x) {
  return 1.f / (1.f + __expf(-x));
}

#define GLOAD_LDS(gptr, lptr) \
  __builtin_amdgcn_global_load_lds( \
      (const __attribute__((address_space(1))) void*)(gptr), \
      (__attribute__((address_space(3))) void*)(lptr), 16, 0, 0)

// raw barrier: asm with memory clobber so no LDS/global op is moved across it
#define SBAR() asm volatile("s_barrier" ::: "memory")

// ---------------- streaming cast att f32 -> bf16 (grid MUST be 50176) ----------------
__global__ void cast_att_k(const float* __restrict__ src, unsigned short* __restrict__ dst) {
  size_t i = ((size_t)blockIdx.x * 256 + threadIdx.x) * 8;   // covers B_*L_*F_
  float4 a = *reinterpret_cast<const float4*>(src + i);
  float4 b = *reinterpret_cast<const float4*>(src + i + 4);
  short8 o;
  o[0] = (short)f2bf(a.x); o[1] = (short)f2bf(a.y); o[2] = (short)f2bf(a.z); o[3] = (short)f2bf(a.w);
  o[4] = (short)f2bf(b.x); o[5] = (short)f2bf(b.y); o[6] = (short)f2bf(b.z); o[7] = (short)f2bf(b.w);
  *reinterpret_cast<short8*>(dst + i) = o;
}

// ---------------- merged weight casts: Wa | Wha | Wg(=Wi|Wh|Wz rows) ----------------
// flat element ranges: [0,1048576) WaB ; [1048576,1572864) WhaB ; rest WgB (4096x4096).
// grid = 18350080/2048 = 8960 blocks.
__global__ void cast_w_all_k(const float* __restrict__ Wa, const float* __restrict__ Wha,
                             const float* __restrict__ Wi, const float* __restrict__ Wh,
                             const float* __restrict__ Wz,
                             unsigned short* __restrict__ WaB, unsigned short* __restrict__ WhaB,
                             unsigned short* __restrict__ WgB) {
  size_t i = ((size_t)blockIdx.x * 256 + threadIdx.x) * 8;
  const float* src;
  unsigned short* dst;
  if (i < 1048576) { src = Wa + i; dst = WaB + i; }
  else if (i < 1572864) { src = Wha + (i - 1048576); dst = WhaB + (i - 1048576); }
  else {
    size_t off = i - 1572864;
    int row = (int)(off >> 12), col = (int)(off & 4095);
    if (col < 1024)       src = Wi + (size_t)row * 1024 + col;
    else if (col < 2048)  src = Wh + (size_t)row * 1024 + (col - 1024);
    else                  src = Wz + (size_t)row * 2048 + (col - 2048);
    dst = WgB + off;
  }
  float4 a = *reinterpret_cast<const float4*>(src);
  float4 b = *reinterpret_cast<const float4*>(src + 4);
  short8 o;
  o[0] = (short)f2bf(a.x); o[1] = (short)f2bf(a.y); o[2] = (short)f2bf(a.z); o[3] = (short)f2bf(a.w);
  o[4] = (short)f2bf(b.x); o[5] = (short)f2bf(b.y); o[6] = (short)f2bf(b.z); o[7] = (short)f2bf(b.w);
  *reinterpret_cast<short8*>(dst) = o;
}

// AgB[256][4096] cols 0..1023 = xt, 1024..2047 = h (z written later)
__global__ void cast_xh_k(const float* __restrict__ xt, const float* __restrict__ h,
                          unsigned short* __restrict__ AgB) {
  int i = (blockIdx.x * 256 + threadIdx.x) * 8;   // covers 256*2048
  int row = i >> 11;
  int col = i & 2047;
  const float* src = (col < 1024) ? (xt + row * 1024 + col) : (h + row * 1024 + (col - 1024));
  float4 a = *reinterpret_cast<const float4*>(src);
  float4 b = *reinterpret_cast<const float4*>(src + 4);
  short8 o;
  o[0] = (short)f2bf(a.x); o[1] = (short)f2bf(a.y); o[2] = (short)f2bf(a.z); o[3] = (short)f2bf(a.w);
  o[4] = (short)f2bf(b.x); o[5] = (short)f2bf(b.y); o[6] = (short)f2bf(b.z); o[7] = (short)f2bf(b.w);
  *reinterpret_cast<short8*>(AgB + (size_t)row * 4096 + col) = o;
}

// ---------------- hlin = h @ Wha^T + bha via MFMA: M=256,N=512,K=1024 ----------------
__global__ __launch_bounds__(256, 2)
void hlin_gemm_k(const unsigned short* __restrict__ AgB, const unsigned short* __restrict__ WhaB,
                 const float* __restrict__ bha, float* __restrict__ hlin) {
  __shared__ unsigned short As[2][64 * 64];
  __shared__ unsigned short Bs[2][128 * 64];
  const int tid = threadIdx.x;
  const int lane = tid & 63, wid = tid >> 6;
  const int wm = wid >> 1, wn = wid & 1;
  const int m0 = blockIdx.y * 64;
  const int n0 = blockIdx.x * 128;
  const int g16 = lane >> 4, l16 = lane & 15;
  const int l7 = l16 & 7;
  f32x4 acc[2][4] = {};

#define STAGE_HL(BUF, KK)                                                                      \
  {                                                                                            \
    _Pragma("unroll")                                                                          \
    for (int it = 0; it < 2; ++it) {                                                           \
      int idx = it * 256 + tid;                                                                \
      int row = idx >> 3;                                                                      \
      int kc = (idx & 7) ^ (row & 7);                                                          \
      GLOAD_LDS(AgB + (size_t)(m0 + row) * 4096 + 1024 + (KK) + kc * 8, &As[BUF][idx * 8]);    \
    }                                                                                          \
    _Pragma("unroll")                                                                          \
    for (int it = 0; it < 4; ++it) {                                                           \
      int idx = it * 256 + tid;                                                                \
      int row = idx >> 3;                                                                      \
      int kc = (idx & 7) ^ (row & 7);                                                          \
      GLOAD_LDS(WhaB + (size_t)(n0 + row) * 1024 + (KK) + kc * 8, &Bs[BUF][idx * 8]);          \
    }                                                                                          \
  }

  STAGE_HL(0, 0);
  STAGE_HL(1, 64);
  asm volatile("s_waitcnt vmcnt(6)" ::: "memory");
  SBAR();
  int cur = 0;
  for (int k0 = 0; k0 < 1024; k0 += 64) {
    #pragma unroll
    for (int ks = 0; ks < 2; ++ks) {
      const int ko = ((ks * 4 + g16) ^ l7) << 3;
      short8 af[2], bfr[4];
      #pragma unroll
      for (int mi = 0; mi < 2; ++mi)
        af[mi] = *reinterpret_cast<const short8*>(&As[cur][(wm * 32 + mi * 16 + l16) * 64 + ko]);
      #pragma unroll
      for (int ni = 0; ni < 4; ++ni)
        bfr[ni] = *reinterpret_cast<const short8*>(&Bs[cur][(wn * 64 + ni * 16 + l16) * 64 + ko]);
      #pragma unroll
      for (int mi = 0; mi < 2; ++mi)
        #pragma unroll
        for (int ni = 0; ni < 4; ++ni)
          acc[mi][ni] = __builtin_amdgcn_mfma_f32_16x16x32_bf16(af[mi], bfr[ni], acc[mi][ni], 0, 0, 0);
    }
    SBAR();
    if (k0 + 128 < 1024) {
      STAGE_HL(cur, k0 + 128);
      asm volatile("s_waitcnt vmcnt(6)" ::: "memory");
    } else {
      asm volatile("s_waitcnt vmcnt(0)" ::: "memory");
    }
    SBAR();
    cur ^= 1;
  }
#undef STAGE_HL

  #pragma unroll
  for (int ni = 0; ni < 4; ++ni) {
    int col = n0 + wn * 64 + ni * 16 + l16;
    float bv = bha[col];
    #pragma unroll
    for (int mi = 0; mi < 2; ++mi)
      #pragma unroll
      for (int j = 0; j < 4; ++j) {
        int m = m0 + wm * 32 + mi * 16 + g16 * 4 + j;
        hlin[(size_t)m * A_ + col] = acc[mi][ni][j] + bv;
      }
  }
}

// ---------------- score GEMM (PRE): counted-vmcnt 2-buffer loop ----------------
// scores8[m][8]: slot = nidx*2 + wn -- each of the 4 N-blocks' two wn-waves owns a slot.
__global__ __launch_bounds__(256, 2)
void score_pre_k(const unsigned short* __restrict__ attB, const unsigned short* __restrict__ WaB,
                 const float* __restrict__ hlin, const float* __restrict__ ba,
                 const float* __restrict__ Wo, float* __restrict__ scores8) {
  __shared__ unsigned short As[2][128 * 64];
  __shared__ unsigned short Bs[2][128 * 64];
  const int tid = threadIdx.x;
  const int lane = tid & 63, wid = tid >> 6;
  const int wm = wid >> 1, wn = wid & 1;
  const int logical = (blockIdx.x & 7) * 196 + (blockIdx.x >> 3);   // 1568 % 8 == 0
  const int m0 = (logical >> 2) * 128;
  const int n0 = (logical & 3) * 128;
  const int g16 = lane >> 4, l16 = lane & 15;
  const int l7 = l16 & 7;
  f32x4 acc[4][4] = {};

#define STAGE_SC(BUF, KK)                                                                \
  {                                                                                      \
    _Pragma("unroll")                                                                    \
    for (int it = 0; it < 4; ++it) {                                                     \
      int idx = it * 256 + tid;                                                          \
      int row = idx >> 3;                                                                \
      int kc = (idx & 7) ^ (row & 7);                                                    \
      GLOAD_LDS(WaB + (size_t)(n0 + row) * F_ + (KK) + kc * 8, &Bs[BUF][idx * 8]);       \
      GLOAD_LDS(attB + (size_t)(m0 + row) * F_ + (KK) + kc * 8, &As[BUF][idx * 8]);      \
    }                                                                                    \
  }

  STAGE_SC(0, 0);
  STAGE_SC(1, 64);
  asm volatile("s_waitcnt vmcnt(8)" ::: "memory");
  SBAR();
  int cur = 0;
  for (int k0 = 0; k0 < F_; k0 += 64) {
    #pragma unroll
    for (int ks = 0; ks < 2; ++ks) {
      const int ko = ((ks * 4 + g16) ^ l7) << 3;
      short8 af[4], bfr[4];
      #pragma unroll
      for (int mi = 0; mi < 4; ++mi)
        af[mi] = *reinterpret_cast<const short8*>(&As[cur][(wm * 64 + mi * 16 + l16) * 64 + ko]);
      #pragma unroll
      for (int ni = 0; ni < 4; ++ni)
        bfr[ni] = *reinterpret_cast<const short8*>(&Bs[cur][(wn * 64 + ni * 16 + l16) * 64 + ko]);
      #pragma unroll
      for (int mi = 0; mi < 4; ++mi)
        #pragma unroll
        for (int ni = 0; ni < 4; ++ni)
          acc[mi][ni] = __builtin_amdgcn_mfma_f32_16x16x32_bf16(af[mi], bfr[ni], acc[mi][ni], 0, 0, 0);
    }
    SBAR();                               // all waves done reading buf[cur]
    if (k0 + 128 < F_) {
      STAGE_SC(cur, k0 + 128);            // stage t+2 into the buffer just freed
      asm volatile("s_waitcnt vmcnt(8)" ::: "memory");   // t+1 done; t+2 stays in flight
    } else {
      asm volatile("s_waitcnt vmcnt(0)" ::: "memory");
    }
    SBAR();                               // buf[cur^1] ready for everyone
    cur ^= 1;
  }
#undef STAGE_SC

  // epilogue: tanh + Wo-weighted reduce over this wave's 64 a-columns
  float wo_v[4], ba_v[4];
  int a_v[4];
  #pragma unroll
  for (int ni = 0; ni < 4; ++ni) {
    int a = n0 + wn * 64 + ni * 16 + l16;
    a_v[ni] = a; wo_v[ni] = Wo[a]; ba_v[ni] = ba[a];
  }
  const int slot = (n0 >> 7) * 2 + wn;
  #pragma unroll
  for (int mi = 0; mi < 4; ++mi) {
    float rs[4];
    #pragma unroll
    for (int j = 0; j < 4; ++j) {
      int m = m0 + wm * 64 + mi * 16 + g16 * 4 + j;
      int b = m / L_;
      const float* hb = hlin + (size_t)b * A_;
      float s = 0.f;
      #pragma unroll
      for (int ni = 0; ni < 4; ++ni) {
        float v = acc[mi][ni][j] + ba_v[ni] + hb[a_v[ni]];
        s += fast_tanh(v) * wo_v[ni];
      }
      rs[j] = s;
    }
    #pragma unroll
    for (int off = 1; off < 16; off <<= 1) {
      #pragma unroll
      for (int j = 0; j < 4; ++j) rs[j] += __shfl_xor(rs[j], off);
    }
    if (l16 == 0) {
      #pragma unroll
      for (int j = 0; j < 4; ++j) {
        int m = m0 + wm * 64 + mi * 16 + g16 * 4 + j;
        scores8[(size_t)m * 8 + slot] = rs[j];
      }
    }
  }
}

// ---------------- score GEMM fallback (no attB): round-4 structure ----------------
__global__ __launch_bounds__(256, 2)
void score_fb_k(const float* __restrict__ att, const unsigned short* __restrict__ WaB,
                const float* __restrict__ hlin, const float* __restrict__ ba,
                const float* __restrict__ Wo, float* __restrict__ scores8) {
  __shared__ unsigned short As[2][128 * 64];
  __shared__ unsigned short Bs[2][128 * 64];
  const int tid = threadIdx.x;
  const int lane = tid & 63, wid = tid >> 6;
  const int wm = wid >> 1, wn = wid & 1;
  const int logical = (blockIdx.x & 7) * 196 + (blockIdx.x >> 3);
  const int m0 = (logical >> 2) * 128;
  const int n0 = (logical & 3) * 128;
  const int g16 = lane >> 4, l16 = lane & 15;
  const int l7 = l16 & 7;
  f32x4 acc[4][4] = {};

#define STAGE_FB(BUF, KK)                                                               \
  {                                                                                     \
    _Pragma("unroll")                                                                   \
    for (int it = 0; it < 4; ++it) {                                                    \
      int idx = it * 256 + tid;                                                         \
      int row = idx >> 3;                                                               \
      int kc = (idx & 7) ^ (row & 7);                                                   \
      GLOAD_LDS(WaB + (size_t)(n0 + row) * F_ + (KK) + kc * 8, &Bs[BUF][idx * 8]);      \
    }                                                                                   \
    _Pragma("unroll")                                                                   \
    for (int it = 0; it < 8; ++it) {                                                    \
      int idx = it * 256 + tid;                                                         \
      int row = idx >> 4, kf = idx & 15;                                                \
      float4 v = *reinterpret_cast<const float4*>(att + (size_t)(m0 + row) * F_ + (KK) + kf * 4); \
      ushort4 o;                                                                        \
      o.x = f2bf(v.x); o.y = f2bf(v.y); o.z = f2bf(v.z); o.w = f2bf(v.w);               \
      int el = row * 64 + (((kf >> 1) ^ (row & 7)) << 3) + ((kf & 1) << 2);             \
      *reinterpret_cast<ushort4*>(&As[BUF][el]) = o;                                    \
    }                                                                                   \
  }

  int cur = 0;
  STAGE_FB(0, 0);
  __syncthreads();
  for (int k0 = 0; k0 < F_; k0 += 64) {
    if (k0 + 64 < F_) STAGE_FB(cur ^ 1, k0 + 64);
    #pragma unroll
    for (int ks = 0; ks < 2; ++ks) {
      const int ko = ((ks * 4 + g16) ^ l7) << 3;
      short8 af[4], bfr[4];
      #pragma unroll
      for (int mi = 0; mi < 4; ++mi)
        af[mi] = *reinterpret_cast<const short8*>(&As[cur][(wm * 64 + mi * 16 + l16) * 64 + ko]);
      #pragma unroll
      for (int ni = 0; ni < 4; ++ni)
        bfr[ni] = *reinterpret_cast<const short8*>(&Bs[cur][(wn * 64 + ni * 16 + l16) * 64 + ko]);
      #pragma unroll
      for (int mi = 0; mi < 4; ++mi)
        #pragma unroll
        for (int ni = 0; ni < 4; ++ni)
          acc[mi][ni] = __builtin_amdgcn_mfma_f32_16x16x32_bf16(af[mi], bfr[ni], acc[mi][ni], 0, 0, 0);
    }
    __syncthreads();
    cur ^= 1;
  }
#undef STAGE_FB

  float wo_v[4], ba_v[4];
  int a_v[4];
  #pragma unroll
  for (int ni = 0; ni < 4; ++ni) {
    int a = n0 + wn * 64 + ni * 16 + l16;
    a_v[ni] = a; wo_v[ni] = Wo[a]; ba_v[ni] = ba[a];
  }
  const int slot = (n0 >> 7) * 2 + wn;
  #pragma unroll
  for (int mi = 0; mi < 4; ++mi) {
    float rs[4];
    #pragma unroll
    for (int j = 0; j < 4; ++j) {
      int m = m0 + wm * 64 + mi * 16 + g16 * 4 + j;
      int b = m / L_;
      const float* hb = hlin + (size_t)b * A_;
      float s = 0.f;
      #pragma unroll
      for (int ni = 0; ni < 4; ++ni) {
        float v = acc[mi][ni][j] + ba_v[ni] + hb[a_v[ni]];
        s += fast_tanh(v) * wo_v[ni];
      }
      rs[j] = s;
    }
    #pragma unroll
    for (int off = 1; off < 16; off <<= 1) {
      #pragma unroll
      for (int j = 0; j < 4; ++j) rs[j] += __shfl_xor(rs[j], off);
    }
    if (l16 == 0) {
      #pragma unroll
      for (int j = 0; j < 4; ++j) {
        int m = m0 + wm * 64 + mi * 16 + g16 * 4 + j;
        scores8[(size_t)m * 8 + slot] = rs[j];
      }
    }
  }
}

// ---------------- fused softmax + z: per (f-half, b) block ----------------
__global__ __launch_bounds__(256)
void z_sm_k(const unsigned short* __restrict__ attB, const float* __restrict__ scores8,
            unsigned short* __restrict__ AgB) {
  __shared__ float sm[L_];
  const int b = blockIdx.y;
  const int tid = threadIdx.x;
  if (tid < L_) {
    const float* p = scores8 + ((size_t)b * L_ + tid) * 8;
    float4 p0 = *reinterpret_cast<const float4*>(p);
    float4 p1 = *reinterpret_cast<const float4*>(p + 4);
    sm[tid] = (p0.x + p0.y) + (p0.z + p0.w) + (p1.x + p1.y) + (p1.z + p1.w);
  }
  __syncthreads();
  float mx = -1e30f;
  for (int l = 0; l < L_; ++l) mx = fmaxf(mx, sm[l]);
  float s = 0.f;
  for (int l = 0; l < L_; ++l) s += __expf(sm[l] - mx);
  const float inv = 1.f / s;
  __syncthreads();
  if (tid < L_) sm[tid] = __expf(sm[tid] - mx) * inv;
  __syncthreads();
  const int f0 = blockIdx.x * 1024 + tid * 4;
  const unsigned short* base = attB + (size_t)b * L_ * F_ + f0;
  float a0 = 0.f, a1 = 0.f, a2 = 0.f, a3 = 0.f;
  #pragma unroll 4
  for (int l = 0; l < L_; ++l) {
    float wl = sm[l];
    ushort4 a = *reinterpret_cast<const ushort4*>(base + (size_t)l * F_);
    a0 += wl * bf2f(a.x); a1 += wl * bf2f(a.y); a2 += wl * bf2f(a.z); a3 += wl * bf2f(a.w);
  }
  ushort4 o;
  o.x = f2bf(a0); o.y = f2bf(a1); o.z = f2bf(a2); o.w = f2bf(a3);
  *reinterpret_cast<ushort4*>(AgB + (size_t)b * 4096 + 2048 + f0) = o;
}

__global__ __launch_bounds__(256)
void z_sm_f32_k(const float* __restrict__ att, const float* __restrict__ scores8,
                unsigned short* __restrict__ AgB) {
  __shared__ float sm[L_];
  const int b = blockIdx.y;
  const int tid = threadIdx.x;
  if (tid < L_) {
    const float* p = scores8 + ((size_t)b * L_ + tid) * 8;
    float4 p0 = *reinterpret_cast<const float4*>(p);
    float4 p1 = *reinterpret_cast<const float4*>(p + 4);
    sm[tid] = (p0.x + p0.y) + (p0.z + p0.w) + (p1.x + p1.y) + (p1.z + p1.w);
  }
  __syncthreads();
  float mx = -1e30f;
  for (int l = 0; l < L_; ++l) mx = fmaxf(mx, sm[l]);
  float s = 0.f;
  for (int l = 0; l < L_; ++l) s += __expf(sm[l] - mx);
  const float inv = 1.f / s;
  __syncthreads();
  if (tid < L_) sm[tid] = __expf(sm[tid] - mx) * inv;
  __syncthreads();
  const int f0 = blockIdx.x * 1024 + tid * 4;
  const float* base = att + (size_t)b * L_ * F_ + f0;
  float a0 = 0.f, a1 = 0.f, a2 = 0.f, a3 = 0.f;
  #pragma unroll 4
  for (int l = 0; l < L_; ++l) {
    float wl = sm[l];
    float4 a = *reinterpret_cast<const float4*>(base + (size_t)l * F_);
    a0 += wl * a.x; a1 += wl * a.y; a2 += wl * a.z; a3 += wl * a.w;
  }
  ushort4 o;
  o.x = f2bf(a0); o.y = f2bf(a1); o.z = f2bf(a2); o.w = f2bf(a3);
  *reinterpret_cast<ushort4*>(AgB + (size_t)b * 4096 + 2048 + f0) = o;
}

// ---------------- gates GEMM: M=256,N=4096,K=4096. BM=64,BN=64, grid(64,4)=256 blocks ----------------
__global__ __launch_bounds__(256, 4)
void gates_gemm_k(const unsigned short* __restrict__ AgB, const unsigned short* __restrict__ WgB,
                  const float* __restrict__ bi, const float* __restrict__ bh,
                  const float* __restrict__ bz, float* __restrict__ sums) {
  __shared__ unsigned short As[2][64 * 64];
  __shared__ unsigned short Bs[2][64 * 64];
  const int tid = threadIdx.x;
  const int lane = tid & 63, wid = tid >> 6;
  const int wm = wid >> 1, wn = wid & 1;
  const int m0 = blockIdx.y * 64;
  const int n0 = blockIdx.x * 64;
  const int g16 = lane >> 4, l16 = lane & 15;
  const int l7 = l16 & 7;
  f32x4 acc[2][2] = {};

#define STAGE_GG(BUF, KK)                                                               \
  {                                                                                     \
    _Pragma("unroll")                                                                   \
    for (int it = 0; it < 2; ++it) {                                                    \
      int idx = it * 256 + tid;                                                         \
      int row = idx >> 3;                                                               \
      int kc = (idx & 7) ^ (row & 7);                                                   \
      GLOAD_LDS(AgB + (size_t)(m0 + row) * 4096 + (KK) + kc * 8, &As[BUF][idx * 8]);    \
      GLOAD_LDS(WgB + (size_t)(n0 + row) * 4096 + (KK) + kc * 8, &Bs[BUF][idx * 8]);    \
    }                                                                                   \
  }

  STAGE_GG(0, 0);
  STAGE_GG(1, 64);
  asm volatile("s_waitcnt vmcnt(4)" ::: "memory");
  SBAR();
  int cur = 0;
  for (int k0 = 0; k0 < 4096; k0 += 64) {
    #pragma unroll
    for (int ks = 0; ks < 2; ++ks) {
      const int ko = ((ks * 4 + g16) ^ l7) << 3;
      short8 af[2], bfr[2];
      #pragma unroll
      for (int mi = 0; mi < 2; ++mi)
        af[mi] = *reinterpret_cast<const short8*>(&As[cur][(wm * 32 + mi * 16 + l16) * 64 + ko]);
      #pragma unroll
      for (int ni = 0; ni < 2; ++ni)
        bfr[ni] = *reinterpret_cast<const short8*>(&Bs[cur][(wn * 32 + ni * 16 + l16) * 64 + ko]);
      #pragma unroll
      for (int mi = 0; mi < 2; ++mi)
        #pragma unroll
        for (int ni = 0; ni < 2; ++ni)
          acc[mi][ni] = __builtin_amdgcn_mfma_f32_16x16x32_bf16(af[mi], bfr[ni], acc[mi][ni], 0, 0, 0);
    }
    SBAR();
    if (k0 + 128 < 4096) {
      STAGE_GG(cur, k0 + 128);
      asm volatile("s_waitcnt vmcnt(4)" ::: "memory");
    } else {
      asm volatile("s_waitcnt vmcnt(0)" ::: "memory");
    }
    SBAR();
    cur ^= 1;
  }
#undef STAGE_GG

  #pragma unroll
  for (int ni = 0; ni < 2; ++ni) {
    int col = n0 + wn * 32 + ni * 16 + l16;
    float bsum = bi[col] + bh[col] + bz[col];
    #pragma unroll
    for (int mi = 0; mi < 2; ++mi)
      #pragma unroll
      for (int j = 0; j < 4; ++j) {
        int m = m0 + wm * 32 + mi * 16 + g16 * 4 + j;
        sums[(size_t)m * 4096 + col] = acc[mi][ni][j] + bsum;
      }
  }
}

// ---------------- gates + zoneout elementwise ----------------
__global__ void final_k(const float* __restrict__ sums, const float* __restrict__ h,
                        const float* __restrict__ c, float* __restrict__ out) {
  int i = blockIdx.x * 256 + threadIdx.x;   // 0 .. B_*H_-1
  int b = i >> 10, hh = i & 1023;
  const float* srow = sums + (size_t)b * 4096;
  float ig = sigmoidf_(srow[hh]);
  float fg = sigmoidf_(srow[1024 + hh]);
  float og = sigmoidf_(srow[2048 + hh]);
  float g  = fast_tanh(srow[3072 + hh]);
  float cv = c[i], hv = h[i];
  float nc = 0.5f * cv + 0.5f * (fg * cv + ig * g);
  float nh = 0.5f * hv + 0.5f * (og * fast_tanh(nc));
  out[i] = nh;
  out[B_ * H_ + i] = nh;
  out[2 * B_ * H_ + i] = nc;
}

extern "C" void kernel_launch(void* const* d_in, const int* in_sizes, int n_in,
                              void* d_out, int out_size, void* d_ws, size_t ws_size,
                              hipStream_t stream) {
  const float* xt  = (const float*)d_in[0];
  const float* att = (const float*)d_in[1];
  const float* h   = (const float*)d_in[2];
  const float* c   = (const float*)d_in[3];
  const float* Wi  = (const float*)d_in[4];
  const float* bi  = (const float*)d_in[5];
  const float* Wh  = (const float*)d_in[6];
  const float* bh  = (const float*)d_in[7];
  const float* Wz  = (const float*)d_in[8];
  const float* bz  = (const float*)d_in[9];
  const float* Wa  = (const float*)d_in[10];
  const float* ba  = (const float*)d_in[11];
  const float* Wha = (const float*)d_in[12];
  const float* bha = (const float*)d_in[13];
  const float* Wo  = (const float*)d_in[14];
  // bo (d_in[15]) is a constant shift under softmax -> dropped.

  char* ws = (char*)d_ws;
  const size_t MB = (size_t)1 << 20;
  unsigned short* WaB  = (unsigned short*)(ws);                // 2 MB
  unsigned short* WhaB = (unsigned short*)(ws + 2 * MB);       // 1 MB
  unsigned short* WgB  = (unsigned short*)(ws + 3 * MB);       // 32 MB
  unsigned short* AgB  = (unsigned short*)(ws + 35 * MB);      // 2 MB
  float* hlin    = (float*)(ws + 37 * MB);                     // 0.5 MB
  float* scores8 = (float*)(ws + 38 * MB);                     // 1.6 MB
  float* sums    = (float*)(ws + 40 * MB);                     // 4 MB
  unsigned short* attB = (unsigned short*)(ws + 48 * MB);      // 196 MB (optional)
  const bool PRE = ws_size >= 245 * MB;
  float* out = (float*)d_out;

  cast_w_all_k<<<8960, 256, 0, stream>>>(Wa, Wha, Wi, Wh, Wz, WaB, WhaB, WgB);
  cast_xh_k<<<256, 256, 0, stream>>>(xt, h, AgB);
  hlin_gemm_k<<<dim3(4, 4), 256, 0, stream>>>(AgB, WhaB, bha, hlin);
  if (PRE) {
    cast_att_k<<<ML, 256, 0, stream>>>(att, attB);   // 50176 blocks exact
    score_pre_k<<<(ML / 128) * (A_ / 128), 256, 0, stream>>>(attB, WaB, hlin, ba, Wo, scores8);
    z_sm_k<<<dim3(2, B_), 256, 0, stream>>>(attB, scores8, AgB);
  } else {
    score_fb_k<<<(ML / 128) * (A_ / 128), 256, 0, stream>>>(att, WaB, hlin, ba, Wo, scores8);
    z_sm_f32_k<<<dim3(2, B_), 256, 0, stream>>>(att, scores8, AgB);
  }
  gates_gemm_k<<<dim3(64, 4), 256, 0, stream>>>(AgB, WgB, bi, bh, bz, sums);
  final_k<<<B_ * H_ / 256, 256, 0, stream>>>(sums, h, c, out);
}

// Round 7
// 418.198 us; speedup vs baseline: 2.1792x; 1.0077x over previous
//
#include <hip/hip_runtime.h>

#define B_ 256
#define E_ 1024
#define H_ 1024
#define F_ 2048
#define L_ 196
#define A_ 512
#define ML (B_ * L_)   // 50176

typedef __attribute__((ext_vector_type(8))) short short8;
typedef __attribute__((ext_vector_type(4))) float f32x4;

__device__ __forceinline__ unsigned short f2bf(float x) {
  unsigned u = __float_as_uint(x);
  unsigned r = (u + 0x7FFFu + ((u >> 16) & 1u)) >> 16;   // RNE
  return (unsigned short)r;
}
__device__ __forceinline__ float bf2f(unsigned short u) {
  return __uint_as_float((unsigned)u << 16);
}
__device__ __forceinline__ float fast_tanh(float x) {
  x = fminf(fmaxf(x, -15.f), 15.f);
  float e = __expf(2.f * x);
  return (e - 1.f) / (e + 1.f);
}
__device__ __forceinline__ float sigmoidf_(float x) {
  return 1.f / (1.f + __expf(-x));
}

#define GLOAD_LDS(gptr, lptr) \
  __builtin_amdgcn_global_load_lds( \
      (const __attribute__((address_space(1))) void*)(gptr), \
      (__attribute__((address_space(3))) void*)(lptr), 16, 0, 0)

#define SBAR() asm volatile("s_barrier" ::: "memory")

// ---------------- merged weight + xh casts ----------------
// flat ranges: [0,1048576) Wa ; [1048576,1572864) Wha ; [1572864,18350080) Wg ;
// [18350080,18874368) xt|h -> AgB cols 0..2047.  grid = 18874368/2048 = 9216 blocks.
__global__ void cast_wx_k(const float* __restrict__ Wa, const float* __restrict__ Wha,
                          const float* __restrict__ Wi, const float* __restrict__ Wh,
                          const float* __restrict__ Wz, const float* __restrict__ xt,
                          const float* __restrict__ h,
                          unsigned short* __restrict__ WaB, unsigned short* __restrict__ WhaB,
                          unsigned short* __restrict__ WgB, unsigned short* __restrict__ AgB) {
  size_t i = ((size_t)blockIdx.x * 256 + threadIdx.x) * 8;
  const float* src;
  unsigned short* dst;
  if (i < 1048576) { src = Wa + i; dst = WaB + i; }
  else if (i < 1572864) { src = Wha + (i - 1048576); dst = WhaB + (i - 1048576); }
  else if (i < 18350080) {
    size_t off = i - 1572864;
    int row = (int)(off >> 12), col = (int)(off & 4095);
    if (col < 1024)       src = Wi + (size_t)row * 1024 + col;
    else if (col < 2048)  src = Wh + (size_t)row * 1024 + (col - 1024);
    else                  src = Wz + (size_t)row * 2048 + (col - 2048);
    dst = WgB + off;
  } else {
    size_t off = i - 18350080;
    int row = (int)(off >> 11), col = (int)(off & 2047);
    src = (col < 1024) ? (xt + (size_t)row * 1024 + col) : (h + (size_t)row * 1024 + (col - 1024));
    dst = AgB + (size_t)row * 4096 + col;
  }
  float4 a = *reinterpret_cast<const float4*>(src);
  float4 b = *reinterpret_cast<const float4*>(src + 4);
  short8 o;
  o[0] = (short)f2bf(a.x); o[1] = (short)f2bf(a.y); o[2] = (short)f2bf(a.z); o[3] = (short)f2bf(a.w);
  o[4] = (short)f2bf(b.x); o[5] = (short)f2bf(b.y); o[6] = (short)f2bf(b.z); o[7] = (short)f2bf(b.w);
  *reinterpret_cast<short8*>(dst) = o;
}

// ---------------- hlin = h @ Wha^T + bha via MFMA: M=256,N=512,K=1024 ----------------
__global__ __launch_bounds__(256, 2)
void hlin_gemm_k(const unsigned short* __restrict__ AgB, const unsigned short* __restrict__ WhaB,
                 const float* __restrict__ bha, float* __restrict__ hlin) {
  __shared__ unsigned short As[2][64 * 64];
  __shared__ unsigned short Bs[2][128 * 64];
  const int tid = threadIdx.x;
  const int lane = tid & 63, wid = tid >> 6;
  const int wm = wid >> 1, wn = wid & 1;
  const int m0 = blockIdx.y * 64;
  const int n0 = blockIdx.x * 128;
  const int g16 = lane >> 4, l16 = lane & 15;
  const int l7 = l16 & 7;
  f32x4 acc[2][4] = {};

#define STAGE_HL(BUF, KK)                                                                      \
  {                                                                                            \
    _Pragma("unroll")                                                                          \
    for (int it = 0; it < 2; ++it) {                                                           \
      int idx = it * 256 + tid;                                                                \
      int row = idx >> 3;                                                                      \
      int kc = (idx & 7) ^ (row & 7);                                                          \
      GLOAD_LDS(AgB + (size_t)(m0 + row) * 4096 + 1024 + (KK) + kc * 8, &As[BUF][idx * 8]);    \
    }                                                                                          \
    _Pragma("unroll")                                                                          \
    for (int it = 0; it < 4; ++it) {                                                           \
      int idx = it * 256 + tid;                                                                \
      int row = idx >> 3;                                                                      \
      int kc = (idx & 7) ^ (row & 7);                                                          \
      GLOAD_LDS(WhaB + (size_t)(n0 + row) * 1024 + (KK) + kc * 8, &Bs[BUF][idx * 8]);          \
    }                                                                                          \
  }

  STAGE_HL(0, 0);
  STAGE_HL(1, 64);
  asm volatile("s_waitcnt vmcnt(6)" ::: "memory");
  SBAR();
  int cur = 0;
  for (int k0 = 0; k0 < 1024; k0 += 64) {
    #pragma unroll
    for (int ks = 0; ks < 2; ++ks) {
      const int ko = ((ks * 4 + g16) ^ l7) << 3;
      short8 af[2], bfr[4];
      #pragma unroll
      for (int mi = 0; mi < 2; ++mi)
        af[mi] = *reinterpret_cast<const short8*>(&As[cur][(wm * 32 + mi * 16 + l16) * 64 + ko]);
      #pragma unroll
      for (int ni = 0; ni < 4; ++ni)
        bfr[ni] = *reinterpret_cast<const short8*>(&Bs[cur][(wn * 64 + ni * 16 + l16) * 64 + ko]);
      #pragma unroll
      for (int mi = 0; mi < 2; ++mi)
        #pragma unroll
        for (int ni = 0; ni < 4; ++ni)
          acc[mi][ni] = __builtin_amdgcn_mfma_f32_16x16x32_bf16(af[mi], bfr[ni], acc[mi][ni], 0, 0, 0);
    }
    SBAR();
    if (k0 + 128 < 1024) {
      STAGE_HL(cur, k0 + 128);
      asm volatile("s_waitcnt vmcnt(6)" ::: "memory");
    } else {
      asm volatile("s_waitcnt vmcnt(0)" ::: "memory");
    }
    SBAR();
    cur ^= 1;
  }
#undef STAGE_HL

  #pragma unroll
  for (int ni = 0; ni < 4; ++ni) {
    int col = n0 + wn * 64 + ni * 16 + l16;
    float bv = bha[col];
    #pragma unroll
    for (int mi = 0; mi < 2; ++mi)
      #pragma unroll
      for (int j = 0; j < 4; ++j) {
        int m = m0 + wm * 32 + mi * 16 + g16 * 4 + j;
        hlin[(size_t)m * A_ + col] = acc[mi][ni][j] + bv;
      }
  }
}

// ---------------- fused cast+score GEMM ----------------
// A: reg-staged f32 att (T14 split: load t+1 before compute t, cvt+ds_write after barrier).
// WB: n0==0 blocks also store converted bf16 to attB (each row written exactly once).
// B: WaB via global_load_lds, pre-swizzled source. Slot-XOR involution both sides.
// scores8[m][8]: slot = (n0>>7)*2 + wn.
template <bool WB>
__global__ __launch_bounds__(256, 2)
void score_fuse_k(const float* __restrict__ att, unsigned short* __restrict__ attB,
                  const unsigned short* __restrict__ WaB,
                  const float* __restrict__ hlin, const float* __restrict__ ba,
                  const float* __restrict__ Wo, float* __restrict__ scores8) {
  __shared__ unsigned short As[2][128 * 64];
  __shared__ unsigned short Bs[2][128 * 64];
  const int tid = threadIdx.x;
  const int lane = tid & 63, wid = tid >> 6;
  const int wm = wid >> 1, wn = wid & 1;
  const int logical = (blockIdx.x & 7) * 196 + (blockIdx.x >> 3);   // 1568 % 8 == 0
  const int m0 = (logical >> 2) * 128;
  const int n0 = (logical & 3) * 128;
  const int g16 = lane >> 4, l16 = lane & 15;
  const int l7 = l16 & 7;
  f32x4 acc[4][4] = {};
  float4 a_reg[8];

#define LOADA(KK)                                                                        \
  {                                                                                      \
    _Pragma("unroll")                                                                    \
    for (int it = 0; it < 8; ++it) {                                                     \
      int idx = it * 256 + tid;                                                          \
      int row = idx >> 4, kf = idx & 15;                                                 \
      a_reg[it] = *reinterpret_cast<const float4*>(att + (size_t)(m0 + row) * F_ + (KK) + kf * 4); \
    }                                                                                    \
  }
#define GLDB(BUF, KK)                                                                    \
  {                                                                                      \
    _Pragma("unroll")                                                                    \
    for (int it = 0; it < 4; ++it) {                                                     \
      int idx = it * 256 + tid;                                                          \
      int row = idx >> 3;                                                                \
      int kc = (idx & 7) ^ (row & 7);                                                    \
      GLOAD_LDS(WaB + (size_t)(n0 + row) * F_ + (KK) + kc * 8, &Bs[BUF][idx * 8]);       \
    }                                                                                    \
  }
#define WRITEA(BUF, KK)                                                                  \
  {                                                                                      \
    _Pragma("unroll")                                                                    \
    for (int it = 0; it < 8; ++it) {                                                     \
      int idx = it * 256 + tid;                                                          \
      int row = idx >> 4, kf = idx & 15;                                                 \
      float4 v = a_reg[it];                                                              \
      ushort4 o;                                                                         \
      o.x = f2bf(v.x); o.y = f2bf(v.y); o.z = f2bf(v.z); o.w = f2bf(v.w);                \
      int el = row * 64 + (((kf >> 1) ^ (row & 7)) << 3) + ((kf & 1) << 2);              \
      *reinterpret_cast<ushort4*>(&As[BUF][el]) = o;                                     \
      if (WB && n0 == 0)                                                                 \
        *reinterpret_cast<ushort4*>(attB + (size_t)(m0 + row) * F_ + (KK) + kf * 4) = o; \
    }                                                                                    \
  }

  // prologue: t=0 staged fully; t=1 loads in flight
  LOADA(0);
  GLDB(0, 0);
  asm volatile("s_waitcnt vmcnt(0)" ::: "memory");   // a_reg(t0) + Bs[0] ready
  WRITEA(0, 0);
  LOADA(64);
  GLDB(1, 64);
  asm volatile("s_waitcnt lgkmcnt(0)" ::: "memory"); // As[0] ds_writes done
  SBAR();

  int cur = 0;
  for (int k0 = 0; k0 < F_; k0 += 64) {
    #pragma unroll
    for (int ks = 0; ks < 2; ++ks) {
      const int ko = ((ks * 4 + g16) ^ l7) << 3;
      short8 af[4], bfr[4];
      #pragma unroll
      for (int mi = 0; mi < 4; ++mi)
        af[mi] = *reinterpret_cast<const short8*>(&As[cur][(wm * 64 + mi * 16 + l16) * 64 + ko]);
      #pragma unroll
      for (int ni = 0; ni < 4; ++ni)
        bfr[ni] = *reinterpret_cast<const short8*>(&Bs[cur][(wn * 64 + ni * 16 + l16) * 64 + ko]);
      #pragma unroll
      for (int mi = 0; mi < 4; ++mi)
        #pragma unroll
        for (int ni = 0; ni < 4; ++ni)
          acc[mi][ni] = __builtin_amdgcn_mfma_f32_16x16x32_bf16(af[mi], bfr[ni], acc[mi][ni], 0, 0, 0);
    }
    SBAR();                                   // all waves done reading buf[cur]
    if (k0 + 64 < F_) {
      asm volatile("s_waitcnt vmcnt(0)" ::: "memory");  // t+1 a_reg + Bs[cur^1] arrived (issued 1 phase ago)
      WRITEA(cur ^ 1, k0 + 64);               // cvt + ds_write + (n0==0) attB store
      if (k0 + 128 < F_) {
        LOADA(k0 + 128);                      // t+2 in flight across next compute
        GLDB(cur, k0 + 128);
      }
      asm volatile("s_waitcnt lgkmcnt(0)" ::: "memory");
    }
    SBAR();
    cur ^= 1;
  }
#undef LOADA
#undef GLDB
#undef WRITEA

  // epilogue: tanh + Wo-weighted reduce over this wave's 64 a-columns
  float wo_v[4], ba_v[4];
  int a_v[4];
  #pragma unroll
  for (int ni = 0; ni < 4; ++ni) {
    int a = n0 + wn * 64 + ni * 16 + l16;
    a_v[ni] = a; wo_v[ni] = Wo[a]; ba_v[ni] = ba[a];
  }
  const int slot = (n0 >> 7) * 2 + wn;
  #pragma unroll
  for (int mi = 0; mi < 4; ++mi) {
    float rs[4];
    #pragma unroll
    for (int j = 0; j < 4; ++j) {
      int m = m0 + wm * 64 + mi * 16 + g16 * 4 + j;
      int b = m / L_;
      const float* hb = hlin + (size_t)b * A_;
      float s = 0.f;
      #pragma unroll
      for (int ni = 0; ni < 4; ++ni) {
        float v = acc[mi][ni][j] + ba_v[ni] + hb[a_v[ni]];
        s += fast_tanh(v) * wo_v[ni];
      }
      rs[j] = s;
    }
    #pragma unroll
    for (int off = 1; off < 16; off <<= 1) {
      #pragma unroll
      for (int j = 0; j < 4; ++j) rs[j] += __shfl_xor(rs[j], off);
    }
    if (l16 == 0) {
      #pragma unroll
      for (int j = 0; j < 4; ++j) {
        int m = m0 + wm * 64 + mi * 16 + g16 * 4 + j;
        scores8[(size_t)m * 8 + slot] = rs[j];
      }
    }
  }
}

// ---------------- fused softmax + z (bf16 attB) ----------------
__global__ __launch_bounds__(256)
void z_sm_k(const unsigned short* __restrict__ attB, const float* __restrict__ scores8,
            unsigned short* __restrict__ AgB) {
  __shared__ float sm[L_];
  const int b = blockIdx.y;
  const int tid = threadIdx.x;
  if (tid < L_) {
    const float* p = scores8 + ((size_t)b * L_ + tid) * 8;
    float4 p0 = *reinterpret_cast<const float4*>(p);
    float4 p1 = *reinterpret_cast<const float4*>(p + 4);
    sm[tid] = (p0.x + p0.y) + (p0.z + p0.w) + (p1.x + p1.y) + (p1.z + p1.w);
  }
  __syncthreads();
  float mx = -1e30f;
  for (int l = 0; l < L_; ++l) mx = fmaxf(mx, sm[l]);
  float s = 0.f;
  for (int l = 0; l < L_; ++l) s += __expf(sm[l] - mx);
  const float inv = 1.f / s;
  __syncthreads();
  if (tid < L_) sm[tid] = __expf(sm[tid] - mx) * inv;
  __syncthreads();
  const int f0 = blockIdx.x * 1024 + tid * 4;
  const unsigned short* base = attB + (size_t)b * L_ * F_ + f0;
  float a0 = 0.f, a1 = 0.f, a2 = 0.f, a3 = 0.f;
  #pragma unroll 4
  for (int l = 0; l < L_; ++l) {
    float wl = sm[l];
    ushort4 a = *reinterpret_cast<const ushort4*>(base + (size_t)l * F_);
    a0 += wl * bf2f(a.x); a1 += wl * bf2f(a.y); a2 += wl * bf2f(a.z); a3 += wl * bf2f(a.w);
  }
  ushort4 o;
  o.x = f2bf(a0); o.y = f2bf(a1); o.z = f2bf(a2); o.w = f2bf(a3);
  *reinterpret_cast<ushort4*>(AgB + (size_t)b * 4096 + 2048 + f0) = o;
}

__global__ __launch_bounds__(256)
void z_sm_f32_k(const float* __restrict__ att, const float* __restrict__ scores8,
                unsigned short* __restrict__ AgB) {
  __shared__ float sm[L_];
  const int b = blockIdx.y;
  const int tid = threadIdx.x;
  if (tid < L_) {
    const float* p = scores8 + ((size_t)b * L_ + tid) * 8;
    float4 p0 = *reinterpret_cast<const float4*>(p);
    float4 p1 = *reinterpret_cast<const float4*>(p + 4);
    sm[tid] = (p0.x + p0.y) + (p0.z + p0.w) + (p1.x + p1.y) + (p1.z + p1.w);
  }
  __syncthreads();
  float mx = -1e30f;
  for (int l = 0; l < L_; ++l) mx = fmaxf(mx, sm[l]);
  float s = 0.f;
  for (int l = 0; l < L_; ++l) s += __expf(sm[l] - mx);
  const float inv = 1.f / s;
  __syncthreads();
  if (tid < L_) sm[tid] = __expf(sm[tid] - mx) * inv;
  __syncthreads();
  const int f0 = blockIdx.x * 1024 + tid * 4;
  const float* base = att + (size_t)b * L_ * F_ + f0;
  float a0 = 0.f, a1 = 0.f, a2 = 0.f, a3 = 0.f;
  #pragma unroll 4
  for (int l = 0; l < L_; ++l) {
    float wl = sm[l];
    float4 a = *reinterpret_cast<const float4*>(base + (size_t)l * F_);
    a0 += wl * a.x; a1 += wl * a.y; a2 += wl * a.z; a3 += wl * a.w;
  }
  ushort4 o;
  o.x = f2bf(a0); o.y = f2bf(a1); o.z = f2bf(a2); o.w = f2bf(a3);
  *reinterpret_cast<ushort4*>(AgB + (size_t)b * 4096 + 2048 + f0) = o;
}

// ---------------- gates GEMM: M=256,N=4096,K=4096. BM=64,BN=64, grid(64,4) ----------------
__global__ __launch_bounds__(256, 4)
void gates_gemm_k(const unsigned short* __restrict__ AgB, const unsigned short* __restrict__ WgB,
                  const float* __restrict__ bi, const float* __restrict__ bh,
                  const float* __restrict__ bz, float* __restrict__ sums) {
  __shared__ unsigned short As[2][64 * 64];
  __shared__ unsigned short Bs[2][64 * 64];
  const int tid = threadIdx.x;
  const int lane = tid & 63, wid = tid >> 6;
  const int wm = wid >> 1, wn = wid & 1;
  const int m0 = blockIdx.y * 64;
  const int n0 = blockIdx.x * 64;
  const int g16 = lane >> 4, l16 = lane & 15;
  const int l7 = l16 & 7;
  f32x4 acc[2][2] = {};

#define STAGE_GG(BUF, KK)                                                               \
  {                                                                                     \
    _Pragma("unroll")                                                                   \
    for (int it = 0; it < 2; ++it) {                                                    \
      int idx = it * 256 + tid;                                                         \
      int row = idx >> 3;                                                               \
      int kc = (idx & 7) ^ (row & 7);                                                   \
      GLOAD_LDS(AgB + (size_t)(m0 + row) * 4096 + (KK) + kc * 8, &As[BUF][idx * 8]);    \
      GLOAD_LDS(WgB + (size_t)(n0 + row) * 4096 + (KK) + kc * 8, &Bs[BUF][idx * 8]);    \
    }                                                                                   \
  }

  STAGE_GG(0, 0);
  STAGE_GG(1, 64);
  asm volatile("s_waitcnt vmcnt(4)" ::: "memory");
  SBAR();
  int cur = 0;
  for (int k0 = 0; k0 < 4096; k0 += 64) {
    #pragma unroll
    for (int ks = 0; ks < 2; ++ks) {
      const int ko = ((ks * 4 + g16) ^ l7) << 3;
      short8 af[2], bfr[2];
      #pragma unroll
      for (int mi = 0; mi < 2; ++mi)
        af[mi] = *reinterpret_cast<const short8*>(&As[cur][(wm * 32 + mi * 16 + l16) * 64 + ko]);
      #pragma unroll
      for (int ni = 0; ni < 2; ++ni)
        bfr[ni] = *reinterpret_cast<const short8*>(&Bs[cur][(wn * 32 + ni * 16 + l16) * 64 + ko]);
      #pragma unroll
      for (int mi = 0; mi < 2; ++mi)
        #pragma unroll
        for (int ni = 0; ni < 2; ++ni)
          acc[mi][ni] = __builtin_amdgcn_mfma_f32_16x16x32_bf16(af[mi], bfr[ni], acc[mi][ni], 0, 0, 0);
    }
    SBAR();
    if (k0 + 128 < 4096) {
      STAGE_GG(cur, k0 + 128);
      asm volatile("s_waitcnt vmcnt(4)" ::: "memory");
    } else {
      asm volatile("s_waitcnt vmcnt(0)" ::: "memory");
    }
    SBAR();
    cur ^= 1;
  }
#undef STAGE_GG

  #pragma unroll
  for (int ni = 0; ni < 2; ++ni) {
    int col = n0 + wn * 32 + ni * 16 + l16;
    float bsum = bi[col] + bh[col] + bz[col];
    #pragma unroll
    for (int mi = 0; mi < 2; ++mi)
      #pragma unroll
      for (int j = 0; j < 4; ++j) {
        int m = m0 + wm * 32 + mi * 16 + g16 * 4 + j;
        sums[(size_t)m * 4096 + col] = acc[mi][ni][j] + bsum;
      }
  }
}

// ---------------- gates + zoneout elementwise ----------------
__global__ void final_k(const float* __restrict__ sums, const float* __restrict__ h,
                        const float* __restrict__ c, float* __restrict__ out) {
  int i = blockIdx.x * 256 + threadIdx.x;   // 0 .. B_*H_-1
  int b = i >> 10, hh = i & 1023;
  const float* srow = sums + (size_t)b * 4096;
  float ig = sigmoidf_(srow[hh]);
  float fg = sigmoidf_(srow[1024 + hh]);
  float og = sigmoidf_(srow[2048 + hh]);
  float g  = fast_tanh(srow[3072 + hh]);
  float cv = c[i], hv = h[i];
  float nc = 0.5f * cv + 0.5f * (fg * cv + ig * g);
  float nh = 0.5f * hv + 0.5f * (og * fast_tanh(nc));
  out[i] = nh;
  out[B_ * H_ + i] = nh;
  out[2 * B_ * H_ + i] = nc;
}

extern "C" void kernel_launch(void* const* d_in, const int* in_sizes, int n_in,
                              void* d_out, int out_size, void* d_ws, size_t ws_size,
                              hipStream_t stream) {
  const float* xt  = (const float*)d_in[0];
  const float* att = (const float*)d_in[1];
  const float* h   = (const float*)d_in[2];
  const float* c   = (const float*)d_in[3];
  const float* Wi  = (const float*)d_in[4];
  const float* bi  = (const float*)d_in[5];
  const float* Wh  = (const float*)d_in[6];
  const float* bh  = (const float*)d_in[7];
  const float* Wz  = (const float*)d_in[8];
  const float* bz  = (const float*)d_in[9];
  const float* Wa  = (const float*)d_in[10];
  const float* ba  = (const float*)d_in[11];
  const float* Wha = (const float*)d_in[12];
  const float* bha = (const float*)d_in[13];
  const float* Wo  = (const float*)d_in[14];
  // bo (d_in[15]) is a constant shift under softmax -> dropped.

  char* ws = (char*)d_ws;
  const size_t MB = (size_t)1 << 20;
  unsigned short* WaB  = (unsigned short*)(ws);                // 2 MB
  unsigned short* WhaB = (unsigned short*)(ws + 2 * MB);       // 1 MB
  unsigned short* WgB  = (unsigned short*)(ws + 3 * MB);       // 32 MB
  unsigned short* AgB  = (unsigned short*)(ws + 35 * MB);      // 2 MB
  float* hlin    = (float*)(ws + 37 * MB);                     // 0.5 MB
  float* scores8 = (float*)(ws + 38 * MB);                     // 1.6 MB
  float* sums    = (float*)(ws + 40 * MB);                     // 4 MB
  unsigned short* attB = (unsigned short*)(ws + 48 * MB);      // 196 MB (optional)
  const bool BIG = ws_size >= 245 * MB;
  float* out = (float*)d_out;

  cast_wx_k<<<9216, 256, 0, stream>>>(Wa, Wha, Wi, Wh, Wz, xt, h, WaB, WhaB, WgB, AgB);
  hlin_gemm_k<<<dim3(4, 4), 256, 0, stream>>>(AgB, WhaB, bha, hlin);
  if (BIG) {
    score_fuse_k<true><<<(ML / 128) * (A_ / 128), 256, 0, stream>>>(att, attB, WaB, hlin, ba, Wo, scores8);
    z_sm_k<<<dim3(2, B_), 256, 0, stream>>>(attB, scores8, AgB);
  } else {
    score_fuse_k<false><<<(ML / 128) * (A_ / 128), 256, 0, stream>>>(att, attB, WaB, hlin, ba, Wo, scores8);
    z_sm_f32_k<<<dim3(2, B_), 256, 0, stream>>>(att, scores8, AgB);
  }
  gates_gemm_k<<<dim3(64, 4), 256, 0, stream>>>(AgB, WgB, bi, bh, bz, sums);
  final_k<<<B_ * H_ / 256, 256, 0, stream>>>(sums, h, c, out);
}

// Round 8
// 380.123 us; speedup vs baseline: 2.3975x; 1.1002x over previous
//
#include <hip/hip_runtime.h>

#define B_ 256
#define E_ 1024
#define H_ 1024
#define F_ 2048
#define L_ 196
#define A_ 512
#define ML (B_ * L_)   // 50176

typedef __attribute__((ext_vector_type(8))) short short8;
typedef __attribute__((ext_vector_type(4))) float f32x4;

__device__ __forceinline__ unsigned short f2bf(float x) {
  unsigned u = __float_as_uint(x);
  unsigned r = (u + 0x7FFFu + ((u >> 16) & 1u)) >> 16;   // RNE
  return (unsigned short)r;
}
__device__ __forceinline__ float bf2f(unsigned short u) {
  return __uint_as_float((unsigned)u << 16);
}
__device__ __forceinline__ float fast_tanh(float x) {
  x = fminf(fmaxf(x, -15.f), 15.f);
  float e = __expf(2.f * x);
  return (e - 1.f) / (e + 1.f);
}
__device__ __forceinline__ float sigmoidf_(float x) {
  return 1.f / (1.f + __expf(-x));
}

#define GLOAD_LDS(gptr, lptr) \
  __builtin_amdgcn_global_load_lds( \
      (const __attribute__((address_space(1))) void*)(gptr), \
      (__attribute__((address_space(3))) void*)(lptr), 16, 0, 0)

#define SBAR() asm volatile("s_barrier" ::: "memory")

// ---------------- merged weight + xh casts ----------------
// flat ranges: [0,1048576) Wa ; [1048576,1572864) Wha ; [1572864,18350080) Wg ;
// [18350080,18874368) xt|h -> AgB cols 0..2047.  grid = 18874368/2048 = 9216 blocks.
__global__ void cast_wx_k(const float* __restrict__ Wa, const float* __restrict__ Wha,
                          const float* __restrict__ Wi, const float* __restrict__ Wh,
                          const float* __restrict__ Wz, const float* __restrict__ xt,
                          const float* __restrict__ h,
                          unsigned short* __restrict__ WaB, unsigned short* __restrict__ WhaB,
                          unsigned short* __restrict__ WgB, unsigned short* __restrict__ AgB) {
  size_t i = ((size_t)blockIdx.x * 256 + threadIdx.x) * 8;
  const float* src;
  unsigned short* dst;
  if (i < 1048576) { src = Wa + i; dst = WaB + i; }
  else if (i < 1572864) { src = Wha + (i - 1048576); dst = WhaB + (i - 1048576); }
  else if (i < 18350080) {
    size_t off = i - 1572864;
    int row = (int)(off >> 12), col = (int)(off & 4095);
    if (col < 1024)       src = Wi + (size_t)row * 1024 + col;
    else if (col < 2048)  src = Wh + (size_t)row * 1024 + (col - 1024);
    else                  src = Wz + (size_t)row * 2048 + (col - 2048);
    dst = WgB + off;
  } else {
    size_t off = i - 18350080;
    int row = (int)(off >> 11), col = (int)(off & 2047);
    src = (col < 1024) ? (xt + (size_t)row * 1024 + col) : (h + (size_t)row * 1024 + (col - 1024));
    dst = AgB + (size_t)row * 4096 + col;
  }
  float4 a = *reinterpret_cast<const float4*>(src);
  float4 b = *reinterpret_cast<const float4*>(src + 4);
  short8 o;
  o[0] = (short)f2bf(a.x); o[1] = (short)f2bf(a.y); o[2] = (short)f2bf(a.z); o[3] = (short)f2bf(a.w);
  o[4] = (short)f2bf(b.x); o[5] = (short)f2bf(b.y); o[6] = (short)f2bf(b.z); o[7] = (short)f2bf(b.w);
  *reinterpret_cast<short8*>(dst) = o;
}

// ---------------- hlin = h @ Wha^T + bha via MFMA: M=256,N=512,K=1024 ----------------
__global__ __launch_bounds__(256, 2)
void hlin_gemm_k(const unsigned short* __restrict__ AgB, const unsigned short* __restrict__ WhaB,
                 const float* __restrict__ bha, float* __restrict__ hlin) {
  __shared__ unsigned short As[2][64 * 64];
  __shared__ unsigned short Bs[2][128 * 64];
  const int tid = threadIdx.x;
  const int lane = tid & 63, wid = tid >> 6;
  const int wm = wid >> 1, wn = wid & 1;
  const int m0 = blockIdx.y * 64;
  const int n0 = blockIdx.x * 128;
  const int g16 = lane >> 4, l16 = lane & 15;
  const int l7 = l16 & 7;
  f32x4 acc[2][4] = {};

#define STAGE_HL(BUF, KK)                                                                      \
  {                                                                                            \
    _Pragma("unroll")                                                                          \
    for (int it = 0; it < 2; ++it) {                                                           \
      int idx = it * 256 + tid;                                                                \
      int row = idx >> 3;                                                                      \
      int kc = (idx & 7) ^ (row & 7);                                                          \
      GLOAD_LDS(AgB + (size_t)(m0 + row) * 4096 + 1024 + (KK) + kc * 8, &As[BUF][idx * 8]);    \
    }                                                                                          \
    _Pragma("unroll")                                                                          \
    for (int it = 0; it < 4; ++it) {                                                           \
      int idx = it * 256 + tid;                                                                \
      int row = idx >> 3;                                                                      \
      int kc = (idx & 7) ^ (row & 7);                                                          \
      GLOAD_LDS(WhaB + (size_t)(n0 + row) * 1024 + (KK) + kc * 8, &Bs[BUF][idx * 8]);          \
    }                                                                                          \
  }

  STAGE_HL(0, 0);
  STAGE_HL(1, 64);
  asm volatile("s_waitcnt vmcnt(6)" ::: "memory");
  SBAR();
  int cur = 0;
  for (int k0 = 0; k0 < 1024; k0 += 64) {
    #pragma unroll
    for (int ks = 0; ks < 2; ++ks) {
      const int ko = ((ks * 4 + g16) ^ l7) << 3;
      short8 af[2], bfr[4];
      #pragma unroll
      for (int mi = 0; mi < 2; ++mi)
        af[mi] = *reinterpret_cast<const short8*>(&As[cur][(wm * 32 + mi * 16 + l16) * 64 + ko]);
      #pragma unroll
      for (int ni = 0; ni < 4; ++ni)
        bfr[ni] = *reinterpret_cast<const short8*>(&Bs[cur][(wn * 64 + ni * 16 + l16) * 64 + ko]);
      #pragma unroll
      for (int mi = 0; mi < 2; ++mi)
        #pragma unroll
        for (int ni = 0; ni < 4; ++ni)
          acc[mi][ni] = __builtin_amdgcn_mfma_f32_16x16x32_bf16(af[mi], bfr[ni], acc[mi][ni], 0, 0, 0);
    }
    SBAR();
    if (k0 + 128 < 1024) {
      STAGE_HL(cur, k0 + 128);
      asm volatile("s_waitcnt vmcnt(6)" ::: "memory");
    } else {
      asm volatile("s_waitcnt vmcnt(0)" ::: "memory");
    }
    SBAR();
    cur ^= 1;
  }
#undef STAGE_HL

  #pragma unroll
  for (int ni = 0; ni < 4; ++ni) {
    int col = n0 + wn * 64 + ni * 16 + l16;
    float bv = bha[col];
    #pragma unroll
    for (int mi = 0; mi < 2; ++mi)
      #pragma unroll
      for (int j = 0; j < 4; ++j) {
        int m = m0 + wm * 32 + mi * 16 + g16 * 4 + j;
        hlin[(size_t)m * A_ + col] = acc[mi][ni][j] + bv;
      }
  }
}

// ---------------- fused cast+score GEMM, depth-2 counted-vmcnt ----------------
// A: f32 att reg-staged, TWO named reg sets (static parity, 2 K-steps per loop iter).
// Loads for t+2 issued BEFORE s_waitcnt vmcnt(12) (waits t+1's 8A+4B only).
// No stores inside the K-loop. scores8[m][8]: slot=(n0>>7)*2+wn.
__global__ __launch_bounds__(256, 2)
void score_fuse_k(const float* __restrict__ att, const unsigned short* __restrict__ WaB,
                  const float* __restrict__ hlin, const float* __restrict__ ba,
                  const float* __restrict__ Wo, float* __restrict__ scores8) {
  __shared__ unsigned short As[2][128 * 64];
  __shared__ unsigned short Bs[2][128 * 64];
  const int tid = threadIdx.x;
  const int lane = tid & 63, wid = tid >> 6;
  const int wm = wid >> 1, wn = wid & 1;
  const int logical = (blockIdx.x & 7) * 196 + (blockIdx.x >> 3);   // 1568 % 8 == 0
  const int m0 = (logical >> 2) * 128;
  const int n0 = (logical & 3) * 128;
  const int g16 = lane >> 4, l16 = lane & 15;
  const int l7 = l16 & 7;
  f32x4 acc[4][4] = {};
  float4 Ra[8], Rb[8];

#define LOADA(REG, KK)                                                                   \
  {                                                                                      \
    _Pragma("unroll")                                                                    \
    for (int it = 0; it < 8; ++it) {                                                     \
      int idx = it * 256 + tid;                                                          \
      int row = idx >> 4, kf = idx & 15;                                                 \
      REG[it] = *reinterpret_cast<const float4*>(att + (size_t)(m0 + row) * F_ + (KK) + kf * 4); \
    }                                                                                    \
  }
#define GLDB(BUF, KK)                                                                    \
  {                                                                                      \
    _Pragma("unroll")                                                                    \
    for (int it = 0; it < 4; ++it) {                                                     \
      int idx = it * 256 + tid;                                                          \
      int row = idx >> 3;                                                                \
      int kc = (idx & 7) ^ (row & 7);                                                    \
      GLOAD_LDS(WaB + (size_t)(n0 + row) * F_ + (KK) + kc * 8, &Bs[BUF][idx * 8]);       \
    }                                                                                    \
  }
#define WRITEA(BUF, REG)                                                                 \
  {                                                                                      \
    _Pragma("unroll")                                                                    \
    for (int it = 0; it < 8; ++it) {                                                     \
      int idx = it * 256 + tid;                                                          \
      int row = idx >> 4, kf = idx & 15;                                                 \
      float4 v = REG[it];                                                                \
      ushort4 o;                                                                         \
      o.x = f2bf(v.x); o.y = f2bf(v.y); o.z = f2bf(v.z); o.w = f2bf(v.w);                \
      int el = row * 64 + (((kf >> 1) ^ (row & 7)) << 3) + ((kf & 1) << 2);              \
      *reinterpret_cast<ushort4*>(&As[BUF][el]) = o;                                     \
    }                                                                                    \
  }
#define COMPUTE(BUF)                                                                     \
  {                                                                                      \
    _Pragma("unroll")                                                                    \
    for (int ks = 0; ks < 2; ++ks) {                                                     \
      const int ko = ((ks * 4 + g16) ^ l7) << 3;                                         \
      short8 af[4], bfr[4];                                                              \
      _Pragma("unroll")                                                                  \
      for (int mi = 0; mi < 4; ++mi)                                                     \
        af[mi] = *reinterpret_cast<const short8*>(&As[BUF][(wm * 64 + mi * 16 + l16) * 64 + ko]); \
      _Pragma("unroll")                                                                  \
      for (int ni = 0; ni < 4; ++ni)                                                     \
        bfr[ni] = *reinterpret_cast<const short8*>(&Bs[BUF][(wn * 64 + ni * 16 + l16) * 64 + ko]); \
      _Pragma("unroll")                                                                  \
      for (int mi = 0; mi < 4; ++mi)                                                     \
        _Pragma("unroll")                                                                \
        for (int ni = 0; ni < 4; ++ni)                                                   \
          acc[mi][ni] = __builtin_amdgcn_mfma_f32_16x16x32_bf16(af[mi], bfr[ni], acc[mi][ni], 0, 0, 0); \
    }                                                                                    \
  }

  // prologue: t0 -> Ra/Bs0 ; t1 -> Rb/Bs1 (in flight)
  LOADA(Ra, 0);  GLDB(0, 0);
  LOADA(Rb, 64); GLDB(1, 64);
  asm volatile("s_waitcnt vmcnt(12)" ::: "memory");   // t0's 12 done; t1's 12 in flight
  WRITEA(0, Ra);                                      // As[0] <- t0
  asm volatile("s_waitcnt lgkmcnt(0)" ::: "memory");
  SBAR();

  // 16 pair-iterations; tiles t=2p (buf0) and t+1 (buf1)
  for (int p = 0; p < 16; ++p) {
    const int t = 2 * p;
    COMPUTE(0);                                       // tile t
    SBAR();
    if (t + 2 < 32) {
      LOADA(Ra, (t + 2) * 64); GLDB(0, (t + 2) * 64); // t+2 into freed buf0/Ra
      asm volatile("s_waitcnt vmcnt(12)" ::: "memory"); // t+1's 12 done; t+2 in flight
    } else {
      asm volatile("s_waitcnt vmcnt(0)" ::: "memory");
    }
    WRITEA(1, Rb);                                    // As[1] <- t+1
    asm volatile("s_waitcnt lgkmcnt(0)" ::: "memory");
    SBAR();
    COMPUTE(1);                                       // tile t+1
    SBAR();
    if (t + 3 < 32) {
      LOADA(Rb, (t + 3) * 64); GLDB(1, (t + 3) * 64); // t+3 into freed buf1/Rb
      asm volatile("s_waitcnt vmcnt(12)" ::: "memory"); // t+2's 12 done
    } else {
      asm volatile("s_waitcnt vmcnt(0)" ::: "memory");
    }
    if (t + 2 < 32) {
      WRITEA(0, Ra);                                  // As[0] <- t+2
    }
    asm volatile("s_waitcnt lgkmcnt(0)" ::: "memory");
    SBAR();
  }
#undef LOADA
#undef GLDB
#undef WRITEA
#undef COMPUTE

  // epilogue: tanh + Wo-weighted reduce over this wave's 64 a-columns
  float wo_v[4], ba_v[4];
  int a_v[4];
  #pragma unroll
  for (int ni = 0; ni < 4; ++ni) {
    int a = n0 + wn * 64 + ni * 16 + l16;
    a_v[ni] = a; wo_v[ni] = Wo[a]; ba_v[ni] = ba[a];
  }
  const int slot = (n0 >> 7) * 2 + wn;
  #pragma unroll
  for (int mi = 0; mi < 4; ++mi) {
    float rs[4];
    #pragma unroll
    for (int j = 0; j < 4; ++j) {
      int m = m0 + wm * 64 + mi * 16 + g16 * 4 + j;
      int b = m / L_;
      const float* hb = hlin + (size_t)b * A_;
      float s = 0.f;
      #pragma unroll
      for (int ni = 0; ni < 4; ++ni) {
        float v = acc[mi][ni][j] + ba_v[ni] + hb[a_v[ni]];
        s += fast_tanh(v) * wo_v[ni];
      }
      rs[j] = s;
    }
    #pragma unroll
    for (int off = 1; off < 16; off <<= 1) {
      #pragma unroll
      for (int j = 0; j < 4; ++j) rs[j] += __shfl_xor(rs[j], off);
    }
    if (l16 == 0) {
      #pragma unroll
      for (int j = 0; j < 4; ++j) {
        int m = m0 + wm * 64 + mi * 16 + g16 * 4 + j;
        scores8[(size_t)m * 8 + slot] = rs[j];
      }
    }
  }
}

// ---------------- fused softmax + z (f32 att) ----------------
__global__ __launch_bounds__(256)
void z_sm_f32_k(const float* __restrict__ att, const float* __restrict__ scores8,
                unsigned short* __restrict__ AgB) {
  __shared__ float sm[L_];
  const int b = blockIdx.y;
  const int tid = threadIdx.x;
  if (tid < L_) {
    const float* p = scores8 + ((size_t)b * L_ + tid) * 8;
    float4 p0 = *reinterpret_cast<const float4*>(p);
    float4 p1 = *reinterpret_cast<const float4*>(p + 4);
    sm[tid] = (p0.x + p0.y) + (p0.z + p0.w) + (p1.x + p1.y) + (p1.z + p1.w);
  }
  __syncthreads();
  float mx = -1e30f;
  for (int l = 0; l < L_; ++l) mx = fmaxf(mx, sm[l]);
  float s = 0.f;
  for (int l = 0; l < L_; ++l) s += __expf(sm[l] - mx);
  const float inv = 1.f / s;
  __syncthreads();
  if (tid < L_) sm[tid] = __expf(sm[tid] - mx) * inv;
  __syncthreads();
  const int f0 = blockIdx.x * 1024 + tid * 4;
  const float* base = att + (size_t)b * L_ * F_ + f0;
  float a0 = 0.f, a1 = 0.f, a2 = 0.f, a3 = 0.f;
  #pragma unroll 4
  for (int l = 0; l < L_; ++l) {
    float wl = sm[l];
    float4 a = *reinterpret_cast<const float4*>(base + (size_t)l * F_);
    a0 += wl * a.x; a1 += wl * a.y; a2 += wl * a.z; a3 += wl * a.w;
  }
  ushort4 o;
  o.x = f2bf(a0); o.y = f2bf(a1); o.z = f2bf(a2); o.w = f2bf(a3);
  *reinterpret_cast<ushort4*>(AgB + (size_t)b * 4096 + 2048 + f0) = o;
}

// ---------------- gates GEMM: M=256,N=4096,K=4096. BM=64,BN=64, grid(64,4) ----------------
__global__ __launch_bounds__(256, 4)
void gates_gemm_k(const unsigned short* __restrict__ AgB, const unsigned short* __restrict__ WgB,
                  const float* __restrict__ bi, const float* __restrict__ bh,
                  const float* __restrict__ bz, float* __restrict__ sums) {
  __shared__ unsigned short As[2][64 * 64];
  __shared__ unsigned short Bs[2][64 * 64];
  const int tid = threadIdx.x;
  const int lane = tid & 63, wid = tid >> 6;
  const int wm = wid >> 1, wn = wid & 1;
  const int m0 = blockIdx.y * 64;
  const int n0 = blockIdx.x * 64;
  const int g16 = lane >> 4, l16 = lane & 15;
  const int l7 = l16 & 7;
  f32x4 acc[2][2] = {};

#define STAGE_GG(BUF, KK)                                                               \
  {                                                                                     \
    _Pragma("unroll")                                                                   \
    for (int it = 0; it < 2; ++it) {                                                    \
      int idx = it * 256 + tid;                                                         \
      int row = idx >> 3;                                                               \
      int kc = (idx & 7) ^ (row & 7);                                                   \
      GLOAD_LDS(AgB + (size_t)(m0 + row) * 4096 + (KK) + kc * 8, &As[BUF][idx * 8]);    \
      GLOAD_LDS(WgB + (size_t)(n0 + row) * 4096 + (KK) + kc * 8, &Bs[BUF][idx * 8]);    \
    }                                                                                   \
  }

  STAGE_GG(0, 0);
  STAGE_GG(1, 64);
  asm volatile("s_waitcnt vmcnt(4)" ::: "memory");
  SBAR();
  int cur = 0;
  for (int k0 = 0; k0 < 4096; k0 += 64) {
    #pragma unroll
    for (int ks = 0; ks < 2; ++ks) {
      const int ko = ((ks * 4 + g16) ^ l7) << 3;
      short8 af[2], bfr[2];
      #pragma unroll
      for (int mi = 0; mi < 2; ++mi)
        af[mi] = *reinterpret_cast<const short8*>(&As[cur][(wm * 32 + mi * 16 + l16) * 64 + ko]);
      #pragma unroll
      for (int ni = 0; ni < 2; ++ni)
        bfr[ni] = *reinterpret_cast<const short8*>(&Bs[cur][(wn * 32 + ni * 16 + l16) * 64 + ko]);
      #pragma unroll
      for (int mi = 0; mi < 2; ++mi)
        #pragma unroll
        for (int ni = 0; ni < 2; ++ni)
          acc[mi][ni] = __builtin_amdgcn_mfma_f32_16x16x32_bf16(af[mi], bfr[ni], acc[mi][ni], 0, 0, 0);
    }
    SBAR();
    if (k0 + 128 < 4096) {
      STAGE_GG(cur, k0 + 128);
      asm volatile("s_waitcnt vmcnt(4)" ::: "memory");
    } else {
      asm volatile("s_waitcnt vmcnt(0)" ::: "memory");
    }
    SBAR();
    cur ^= 1;
  }
#undef STAGE_GG

  #pragma unroll
  for (int ni = 0; ni < 2; ++ni) {
    int col = n0 + wn * 32 + ni * 16 + l16;
    float bsum = bi[col] + bh[col] + bz[col];
    #pragma unroll
    for (int mi = 0; mi < 2; ++mi)
      #pragma unroll
      for (int j = 0; j < 4; ++j) {
        int m = m0 + wm * 32 + mi * 16 + g16 * 4 + j;
        sums[(size_t)m * 4096 + col] = acc[mi][ni][j] + bsum;
      }
  }
}

// ---------------- gates + zoneout elementwise ----------------
__global__ void final_k(const float* __restrict__ sums, const float* __restrict__ h,
                        const float* __restrict__ c, float* __restrict__ out) {
  int i = blockIdx.x * 256 + threadIdx.x;   // 0 .. B_*H_-1
  int b = i >> 10, hh = i & 1023;
  const float* srow = sums + (size_t)b * 4096;
  float ig = sigmoidf_(srow[hh]);
  float fg = sigmoidf_(srow[1024 + hh]);
  float og = sigmoidf_(srow[2048 + hh]);
  float g  = fast_tanh(srow[3072 + hh]);
  float cv = c[i], hv = h[i];
  float nc = 0.5f * cv + 0.5f * (fg * cv + ig * g);
  float nh = 0.5f * hv + 0.5f * (og * fast_tanh(nc));
  out[i] = nh;
  out[B_ * H_ + i] = nh;
  out[2 * B_ * H_ + i] = nc;
}

extern "C" void kernel_launch(void* const* d_in, const int* in_sizes, int n_in,
                              void* d_out, int out_size, void* d_ws, size_t ws_size,
                              hipStream_t stream) {
  const float* xt  = (const float*)d_in[0];
  const float* att = (const float*)d_in[1];
  const float* h   = (const float*)d_in[2];
  const float* c   = (const float*)d_in[3];
  const float* Wi  = (const float*)d_in[4];
  const float* bi  = (const float*)d_in[5];
  const float* Wh  = (const float*)d_in[6];
  const float* bh  = (const float*)d_in[7];
  const float* Wz  = (const float*)d_in[8];
  const float* bz  = (const float*)d_in[9];
  const float* Wa  = (const float*)d_in[10];
  const float* ba  = (const float*)d_in[11];
  const float* Wha = (const float*)d_in[12];
  const float* bha = (const float*)d_in[13];
  const float* Wo  = (const float*)d_in[14];
  // bo (d_in[15]) is a constant shift under softmax -> dropped.

  char* ws = (char*)d_ws;
  const size_t MB = (size_t)1 << 20;
  unsigned short* WaB  = (unsigned short*)(ws);                // 2 MB
  unsigned short* WhaB = (unsigned short*)(ws + 2 * MB);       // 1 MB
  unsigned short* WgB  = (unsigned short*)(ws + 3 * MB);       // 32 MB
  unsigned short* AgB  = (unsigned short*)(ws + 35 * MB);      // 2 MB
  float* hlin    = (float*)(ws + 37 * MB);                     // 0.5 MB
  float* scores8 = (float*)(ws + 38 * MB);                     // 1.6 MB
  float* sums    = (float*)(ws + 40 * MB);                     // 4 MB
  float* out = (float*)d_out;

  cast_wx_k<<<9216, 256, 0, stream>>>(Wa, Wha, Wi, Wh, Wz, xt, h, WaB, WhaB, WgB, AgB);
  hlin_gemm_k<<<dim3(4, 4), 256, 0, stream>>>(AgB, WhaB, bha, hlin);
  score_fuse_k<<<(ML / 128) * (A_ / 128), 256, 0, stream>>>(att, WaB, hlin, ba, Wo, scores8);
  z_sm_f32_k<<<dim3(2, B_), 256, 0, stream>>>(att, scores8, AgB);
  gates_gemm_k<<<dim3(64, 4), 256, 0, stream>>>(AgB, WgB, bi, bh, bz, sums);
  final_k<<<B_ * H_ / 256, 256, 0, stream>>>(sums, h, c, out);
}